// Round 9
// baseline (326.092 us; speedup 1.0000x reference)
//
#include <hip/hip_runtime.h>
#include <hip/hip_bf16.h>
#include <stdint.h>
#include <string.h>

#define NNODES 16384
#define GIN 256      // input feature dim
#define NG 64        // nodes per graph (N/G)
#define NGRAPH 256
#define FDIM 64      // per-head out dim
#define CDIM 512     // H*F

typedef __attribute__((ext_vector_type(8))) short bf16x8;
typedef __attribute__((ext_vector_type(4))) float f32x4;
typedef __attribute__((ext_vector_type(2))) float f32x2;

__device__ __forceinline__ float bf2f(unsigned short u){
  union { unsigned int i; float f; } w; w.i = ((unsigned int)u) << 16; return w.f;
}

// unpack two bf16 packed in a uint to an f32 pair
__device__ __forceinline__ f32x2 unpk2(unsigned int u){
  union { unsigned int i; float f; } a, b;
  a.i = u << 16; b.i = u & 0xffff0000u;
  return (f32x2){a.f, b.f};
}

// CDNA full-rate packed f32 VALU (VOP3P) — one instruction covers 2 channels
__device__ __forceinline__ f32x2 pk_add(f32x2 a, f32x2 b){
  f32x2 d; asm("v_pk_add_f32 %0, %1, %2" : "=v"(d) : "v"(a), "v"(b)); return d;
}
__device__ __forceinline__ f32x2 pk_mul(f32x2 a, f32x2 b){
  f32x2 d; asm("v_pk_mul_f32 %0, %1, %2" : "=v"(d) : "v"(a), "v"(b)); return d;
}
__device__ __forceinline__ f32x2 pk_fma(f32x2 a, f32x2 b, f32x2 c){
  f32x2 d; asm("v_pk_fma_f32 %0, %1, %2, %3" : "=v"(d) : "v"(a), "v"(b), "v"(c)); return d;
}

union PK8 { __hip_bfloat16 h[8]; uint4 v; };

__device__ __forceinline__ void async16(const void* g, void* l){
  __builtin_amdgcn_global_load_lds(
      (const __attribute__((address_space(1))) unsigned int*)g,
      (__attribute__((address_space(3))) unsigned int*)l, 16, 0, 0);
}

// ---------- local dtype detection ----------
__device__ __forceinline__ int is_f32(const unsigned short* __restrict__ x){
  int bad = 0;
  #pragma unroll
  for (int j = 0; j < 64; j++){
    float f = bf2f(x[j*4]);
    if (!(fabsf(f) < 1e4f)) bad++;
  }
  return bad > 4;
}

// ---------- small-vector conversion to fp32 (17 segments) + deg zeroing ----------
struct CArgs {
  const void* p[17];
  int cum[18];
};

__global__ void k_convert(CArgs a, const unsigned short* __restrict__ x,
                          float* __restrict__ dst, int total, int* __restrict__ deg){
  int isf32 = is_f32(x);
  int totAll = total + NNODES;
  for (int idx = blockIdx.x*blockDim.x + threadIdx.x; idx < totAll; idx += gridDim.x*blockDim.x){
    if (idx >= total){ deg[idx - total] = 0; continue; }
    int seg = 0;
    while (idx >= a.cum[seg+1]) seg++;
    int off = idx - a.cum[seg];
    float v;
    if (isf32) v = ((const float*)a.p[seg])[off];
    else       v = bf2f(((const unsigned short*)a.p[seg])[off]);
    dst[idx] = v;
  }
}

// ---------- x -> bf16 + edge degree count (deg pre-zeroed by k_convert) ----------
__global__ void k_xconv_count(const void* __restrict__ xin,
                              __hip_bfloat16* __restrict__ xbf, int total,
                              const int* __restrict__ edst, int E, int* __restrict__ deg){
  int isf32 = is_f32((const unsigned short*)xin);
  for (int idx = blockIdx.x*blockDim.x + threadIdx.x; idx < total; idx += gridDim.x*blockDim.x){
    float v;
    if (isf32) v = ((const float*)xin)[idx];
    else       v = bf2f(((const unsigned short*)xin)[idx]);
    xbf[idx] = __float2bfloat16(v);
  }
  for (int e = blockIdx.x*blockDim.x + threadIdx.x; e < E; e += gridDim.x*blockDim.x)
    atomicAdd(&deg[edst[e]], 1);
}

// ---------- merged transpose from RAW weights ----------
struct TArgs {
  const void* W[6];
  __hip_bfloat16* Wt[6];
  int K[6];
};

__global__ void k_transpose_all(TArgs t, const unsigned short* __restrict__ x){
  int isf32 = is_f32(x);
  int seg = blockIdx.z;
  int K = t.K[seg];
  int n0 = blockIdx.x*32, k0 = blockIdx.y*32;
  if (k0 >= K) return;
  const void* W = t.W[seg];
  __hip_bfloat16* Wt = t.Wt[seg];
  __shared__ float tl[32][33];
  for (int r = threadIdx.y; r < 32; r += 8){
    size_t idx = (size_t)(k0 + r)*CDIM + n0 + threadIdx.x;
    tl[r][threadIdx.x] = isf32 ? ((const float*)W)[idx] : bf2f(((const unsigned short*)W)[idx]);
  }
  __syncthreads();
  for (int r = threadIdx.y; r < 32; r += 8)
    Wt[(size_t)(n0 + r)*K + k0 + threadIdx.x] = __float2bfloat16(tl[threadIdx.x][r]);
}

// ---------- CSR build (by dst), payload = src node ----------
__global__ void k_scan(const int* __restrict__ deg, int* __restrict__ off, int* __restrict__ cur){
  __shared__ int ss[256];
  int t = threadIdx.x;
  const int4* d4 = (const int4*)(deg + t*64);
  int4 buf[16];
  int s = 0;
  #pragma unroll
  for (int j = 0; j < 16; j++){
    buf[j] = d4[j];
    s += buf[j].x + buf[j].y + buf[j].z + buf[j].w;
  }
  ss[t] = s;
  __syncthreads();
  for (int o = 1; o < 256; o <<= 1){
    int v = 0;
    if (t >= o) v = ss[t - o];
    __syncthreads();
    if (t >= o) ss[t] += v;
    __syncthreads();
  }
  int run = ss[t] - s;  // exclusive prefix
  int4* o4 = (int4*)(off + t*64);
  int4* c4 = (int4*)(cur + t*64);
  #pragma unroll
  for (int j = 0; j < 16; j++){
    int4 v;
    v.x = run; run += buf[j].x;
    v.y = run; run += buf[j].y;
    v.z = run; run += buf[j].z;
    v.w = run; run += buf[j].w;
    o4[j] = v; c4[j] = v;
  }
  if (t == 255) off[NNODES] = run;
}

__global__ void k_fill(const int* __restrict__ esrc, const int* __restrict__ edst, int E,
                       int* __restrict__ cur, int* __restrict__ srcs){
  int e = blockIdx.x*blockDim.x + threadIdx.x;
  if (e < E){
    int pos = atomicAdd(&cur[edst[e]], 1);
    srcs[pos] = esrc[e];
  }
}

// ---------- bf16 MFMA GEMM, 256x256 tile, BK=64, 8-wave 8-phase counted-vmcnt schedule ----------
// (verified; <=15us marginal/launch at K=512 per round-6 REPS ablation top-5 bound)
// NOTE: tail-wrap garbage stages are LOAD-BEARING for the vmcnt(4) ledger — do not remove.
#define GBAR  do { asm volatile("" ::: "memory"); __builtin_amdgcn_s_barrier(); asm volatile("" ::: "memory"); } while(0)

#define PHASE(BUF, MH, NH, LA, LB, SBUF, SISB, SUNIT, ST, DOVM)                                   \
  { if (LA){ _Pragma("unroll") for (int ko_=0;ko_<2;ko_++)                                        \
               _Pragma("unroll") for (int ii_=0;ii_<4;ii_++) Afr[ko_][ii_]=rdA(BUF,MH,ii_,ko_); } \
    if (LB){ _Pragma("unroll") for (int ko_=0;ko_<2;ko_++)                                        \
               _Pragma("unroll") for (int jj_=0;jj_<2;jj_++) Bfr[ko_][jj_]=rdB(BUF,NH,jj_,ko_); } \
    stage(SBUF,SISB,SUNIT,ST);                                                                    \
    if (DOVM) asm volatile("s_waitcnt vmcnt(4)" ::: "memory");                                    \
    GBAR;                                                                                         \
    __builtin_amdgcn_s_setprio(1);                                                                \
    _Pragma("unroll") for (int ii_=0;ii_<4;ii_++)                                                 \
      _Pragma("unroll") for (int jj_=0;jj_<2;jj_++)                                               \
        _Pragma("unroll") for (int ko_=0;ko_<2;ko_++)                                             \
          acc[(MH)*4+ii_][(NH)*2+jj_] = __builtin_amdgcn_mfma_f32_16x16x32_bf16(                  \
              Afr[ko_][ii_], Bfr[ko_][jj_], acc[(MH)*4+ii_][(NH)*2+jj_], 0, 0, 0);                \
    __builtin_amdgcn_s_setprio(0);                                                                \
    GBAR; }

__global__ __launch_bounds__(512, 2) void k_gemm256(
    const __hip_bfloat16* __restrict__ A,
    const __hip_bfloat16* __restrict__ Wtl, const __hip_bfloat16* __restrict__ Wtr,
    __hip_bfloat16* __restrict__ Cl, __hip_bfloat16* __restrict__ Cr, int K){
  const __hip_bfloat16* Wt = blockIdx.z ? Wtr : Wtl;
  __hip_bfloat16*       C  = blockIdx.z ? Cr  : Cl;
  __shared__ __align__(128) char lds[131072];   // A: [0,64K)  B: [64K,128K)
  const int tid = threadIdx.x;
  const int w = tid >> 6, lane = tid & 63;
  const int wm = w >> 2, wn = w & 3;
  const int l16 = lane & 15, c4 = lane >> 4;
  const int row0 = blockIdx.x * 256, col0 = blockIdx.y * 256;
  const int NT = K >> 6;

  f32x4 acc[8][4];
  bf16x8 Afr[2][4];   // [ko][ii]  current mh
  bf16x8 Bfr[2][2];   // [ko][jj]  current nh

  const __hip_bfloat16* Ag = A  + (size_t)row0 * K;
  const __hip_bfloat16* Bg = Wt + (size_t)col0 * K;

  auto stage = [&](int buf, int isB, int unit, int t){
    int k0 = (t < NT ? t : t - NT) << 6;        // tail wrap -> dead-region garbage stage
    #pragma unroll
    for (int j = 0; j < 2; j++){
      int u0 = (w*2 + j) * 8;                   // wave-uniform
      int uidx = u0 + (lane >> 3);              // 0..127 within unit
      int row, rs;
      if (!isB){ row = (uidx & 63) | ((uidx & 64) << 1) | (unit << 6);
                 rs  = (u0   & 63) | ((u0   & 64) << 1) | (unit << 6); }
      else     { row = ((uidx & 96) << 1) | (uidx & 31) | (unit << 5);
                 rs  = ((u0   & 96) << 1) | (u0   & 31) | (unit << 5); }
      int chunk = (lane & 7) ^ (uidx & 7);      // inverse-swizzled global source
      const __hip_bfloat16* gp = (isB ? Bg : Ag) + (size_t)row * K + k0 + chunk * 8;
      async16(gp, lds + (isB ? 65536 : 0) + buf * 32768 + rs * 128);
    }
  };

  auto rdA = [&](int buf, int mh, int ii, int ko)->bf16x8{
    int row = wm*128 + mh*64 + ii*16 + l16;
    int chunk = ((ko<<2) + c4) ^ (l16 & 7);
    return *(const bf16x8*)(lds + buf*32768 + row*128 + chunk*16);
  };
  auto rdB = [&](int buf, int nh, int jj, int ko)->bf16x8{
    int row = wn*64 + nh*32 + jj*16 + l16;
    int chunk = ((ko<<2) + c4) ^ (l16 & 7);
    return *(const bf16x8*)(lds + 65536 + buf*32768 + row*128 + chunk*16);
  };

  #pragma unroll
  for (int i = 0; i < 8; i++)
    #pragma unroll
    for (int j = 0; j < 4; j++) acc[i][j] = (f32x4){0.f,0.f,0.f,0.f};

  // prologue: full tile0 + A(1)u0 + B(1)u1, allow last 2 units in flight
  stage(0,0,0,0); stage(0,1,1,0); stage(0,0,1,0); stage(0,1,0,0);
  stage(1,0,0,1); stage(1,1,1,1);
  asm volatile("s_waitcnt vmcnt(4)" ::: "memory");
  GBAR;

  for (int t = 0; t < NT; t += 2){
    PHASE(0, 0, 0, 1, 1, 1, 0, 1, t+1, 0)   // ph1: stage A(t+1)u1 -> buf1
    PHASE(0, 0, 1, 0, 1, 1, 1, 0, t+1, 0)   // ph2: stage B(t+1)u0 -> buf1
    PHASE(0, 1, 1, 1, 0, 0, 0, 0, t+2, 0)   // ph3: stage A(t+2)u0 -> buf0
    PHASE(0, 1, 0, 0, 1, 0, 1, 1, t+2, 1)   // ph4: stage B(t+2)u1 -> buf0, vmcnt(4)
    PHASE(1, 0, 0, 1, 1, 0, 0, 1, t+2, 0)   // ph5: stage A(t+2)u1 -> buf0
    PHASE(1, 0, 1, 0, 1, 0, 1, 0, t+2, 0)   // ph6: stage B(t+2)u0 -> buf0
    PHASE(1, 1, 1, 1, 0, 1, 0, 0, t+3, 0)   // ph7: stage A(t+3)u0 -> buf1
    PHASE(1, 1, 0, 0, 1, 1, 1, 1, t+3, 1)   // ph8: stage B(t+3)u1 -> buf1, vmcnt(4)
  }

  // drain wrapped garbage stages before reusing LDS as C-staging tile
  asm volatile("s_waitcnt vmcnt(0)" ::: "memory");
  GBAR;
  {
    __hip_bfloat16* ct = (__hip_bfloat16*)lds;   // [256][256] bf16 = 128 KiB
    #pragma unroll
    for (int i = 0; i < 8; i++)
      #pragma unroll
      for (int j = 0; j < 4; j++)
        #pragma unroll
        for (int r = 0; r < 4; r++){
          int rl = wm*128 + i*16 + c4*4 + r;
          int cl = wn*64  + j*16 + l16;
          ct[rl*256 + cl] = __float2bfloat16(acc[i][j][r]);
        }
  }
  // ds_write -> barrier -> ds_read requires the writer's lgkmcnt(0) (ISA §8)
  asm volatile("s_waitcnt lgkmcnt(0)" ::: "memory");
  GBAR;
  #pragma unroll
  for (int s = 0; s < 16; s++){
    int seg = s*512 + tid;            // 8192 x 16B
    int rl = seg >> 5, ch = seg & 31;
    uint4 v = *(const uint4*)(lds + rl*512 + ch*16);
    *(uint4*)((char*)(C + (size_t)(row0 + rl)*CDIM + col0) + ch*16) = v;
  }
}

// ---------- fused GATv2 edge phase: 4 waves/block, 4 nodes/wave, packed-f32 VALU ----------
// Round-8 post-mortem: 64-thr blocks removed retirement imbalance but HALVED occupancy
// (16 wg/CU limit -> 16 waves/CU vs ~28 for 256-thr blocks at 68 VGPR). This version:
// 256-thr blocks (full occupancy), 4 independent waves, each wave owns 4 CONSECUTIVE
// nodes -> block retires on max-of-4 sums-of-4 degrees (E[max]/mean ~1.17 vs 1.45).
// Packed VALU + __expf kept from round 8. Per-node FP order identical.
template<int CONCAT>
__global__ __launch_bounds__(256) void k_fused_attn(
    const __hip_bfloat16* __restrict__ XL, const __hip_bfloat16* __restrict__ XR,
    const float* __restrict__ att,
    const int* __restrict__ off, const int* __restrict__ srcs,
    const float* __restrict__ bias, __hip_bfloat16* __restrict__ OUT){
  int wave = threadIdx.x >> 6, lane = threadIdx.x & 63;

  const f32x2* atp = (const f32x2*)(att + lane*8);
  f32x2 at2[4] = {atp[0], atp[1], atp[2], atp[3]};
  const f32x2 c02 = {0.2f, 0.2f};
  const float4* bp = (const float4*)(bias + (CONCAT ? lane*8 : (lane & 7)*8));
  float4 b0v = bp[0], b1v = bp[1];
  float bb[8] = {b0v.x, b0v.y, b0v.z, b0v.w, b1v.x, b1v.y, b1v.z, b1v.w};

  #pragma unroll
  for (int t = 0; t < 4; t++){
    int d = blockIdx.x*16 + wave*4 + t;

    uint4 xru = *(const uint4*)((const char*)XR + ((size_t)d*CDIM + lane*8)*2);
    f32x2 xr2[4] = {unpk2(xru.x), unpk2(xru.y), unpk2(xru.z), unpk2(xru.w)};

    f32x2 acc2[4];
    #pragma unroll
    for (int k = 0; k < 4; k++) acc2[k] = (f32x2){0.f, 0.f};
    float den = 0.f;

    int beg = off[d], end = off[d+1];   // end > beg guaranteed (self-loops appended)

    uint4 rwA[4], rwB[4];

    auto ldgth = [&](int i, uint4* rw){
      int n = end - i;                       // wave-uniform, >= 1
      int s0 = srcs[i];
      int s1 = n > 1 ? srcs[i+1] : s0;
      int s2 = n > 2 ? srcs[i+2] : s0;
      int s3 = n > 3 ? srcs[i+3] : s0;
      rw[0] = *(const uint4*)((const char*)XL + ((size_t)s0*CDIM + lane*8)*2);
      rw[1] = *(const uint4*)((const char*)XL + ((size_t)s1*CDIM + lane*8)*2);
      rw[2] = *(const uint4*)((const char*)XL + ((size_t)s2*CDIM + lane*8)*2);
      rw[3] = *(const uint4*)((const char*)XL + ((size_t)s3*CDIM + lane*8)*2);
    };

    auto compute = [&](const uint4* rw, int n){
      #pragma unroll
      for (int e = 0; e < 4; e++){
        if (e < n){                          // wave-uniform branch
          f32x2 xv2[4] = {unpk2(rw[e].x), unpk2(rw[e].y), unpk2(rw[e].z), unpk2(rw[e].w)};
          f32x2 v2 = (f32x2){0.f, 0.f};
          #pragma unroll
          for (int k = 0; k < 4; k++){
            f32x2 m2 = pk_add(xv2[k], xr2[k]);
            f32x2 t2 = pk_mul(m2, c02);
            f32x2 l2 = (f32x2){fmaxf(m2[0], t2[0]), fmaxf(m2[1], t2[1])};  // leaky
            v2 = pk_fma(l2, at2[k], v2);
          }
          float v = v2[0] + v2[1];
          v += __shfl_xor(v, 1); v += __shfl_xor(v, 2); v += __shfl_xor(v, 4);
          float p = __expf(v);
          den += p;
          f32x2 p2 = (f32x2){p, p};
          #pragma unroll
          for (int k = 0; k < 4; k++) acc2[k] = pk_fma(p2, xv2[k], acc2[k]);
        }
      }
    };

    ldgth(beg, rwA);
    int i = beg;
    while (true){
      int iB = i + 4;
      if (iB >= end){ compute(rwA, end - i); break; }
      ldgth(iB, rwB);                        // issue next group before waiting on rwA
      compute(rwA, 4);
      int iA = iB + 4;
      if (iA >= end){ compute(rwB, end - iB); break; }
      ldgth(iA, rwA);
      compute(rwB, 4);
      i = iA;
    }

    float inv = 1.f / (den + 1e-16f);

    if (CONCAT){
      PK8 pk;
      #pragma unroll
      for (int k = 0; k < 4; k++){
        pk.h[2*k]   = __float2bfloat16(acc2[k][0]*inv + bb[2*k]);
        pk.h[2*k+1] = __float2bfloat16(acc2[k][1]*inv + bb[2*k+1]);
      }
      *(uint4*)((char*)OUT + ((size_t)d*CDIM + lane*8)*2) = pk.v;
    } else {
      float r[8];
      #pragma unroll
      for (int k = 0; k < 4; k++){ r[2*k] = acc2[k][0]*inv; r[2*k+1] = acc2[k][1]*inv; }
      #pragma unroll
      for (int o = 8; o < 64; o <<= 1)
        #pragma unroll
        for (int j = 0; j < 8; j++) r[j] += __shfl_xor(r[j], o);
      if (lane < 8){
        PK8 pk;
        #pragma unroll
        for (int j = 0; j < 8; j++)
          pk.h[j] = __float2bfloat16(r[j]*0.125f + bb[j]);
        *(uint4*)((char*)OUT + ((size_t)d*FDIM + lane*8)*2) = pk.v;
      }
    }
  }
}

// ---------- GraphNorm + ReLU (layers 1-2) ----------
__global__ void k_graphnorm_relu(const __hip_bfloat16* __restrict__ X, const float* __restrict__ w,
    const float* __restrict__ b, const float* __restrict__ ms,
    __hip_bfloat16* __restrict__ Y, int C){
  int g = blockIdx.x;
  int c = threadIdx.x;
  const __hip_bfloat16* xg = X + (size_t)g * NG * C + c;
  __hip_bfloat16* yg = Y + (size_t)g * NG * C + c;
  float v[NG];
  float s1 = 0.f, s2 = 0.f;
  #pragma unroll
  for (int i = 0; i < NG; i++){
    v[i] = __bfloat162float(xg[(size_t)i*C]);
    s1 += v[i]; s2 += v[i]*v[i];
  }
  float mean = s1 * (1.f/NG);
  float m = ms[c];
  float var = s2 * (1.f/NG) - 2.f*m*mean*mean + m*m*mean*mean;
  float inv = rsqrtf(var + 1e-5f);
  float ww = w[c], bb = b[c];
  #pragma unroll
  for (int i = 0; i < NG; i++){
    float y = fmaf(ww * (v[i] - m*mean), inv, bb);
    yg[(size_t)i*C] = __float2bfloat16(y > 0.f ? y : 0.f);
  }
}

// ---------- layer 3: GraphNorm + ReLU + mean-pool + linear [64->2], fused ----------
__global__ void k_norm_pool(const __hip_bfloat16* __restrict__ X, const float* __restrict__ w,
    const float* __restrict__ b, const float* __restrict__ ms,
    const float* __restrict__ Wlin, const float* __restrict__ blin,
    void* out, const unsigned short* __restrict__ xus){
  int g = blockIdx.x, c = threadIdx.x;  // 64 threads, c = channel
  const __hip_bfloat16* xg = X + (size_t)g * NG * FDIM + c;
  float v[NG];
  float s1 = 0.f, s2 = 0.f;
  #pragma unroll
  for (int i = 0; i < NG; i++){
    v[i] = __bfloat162float(xg[(size_t)i*FDIM]);
    s1 += v[i]; s2 += v[i]*v[i];
  }
  float mean = s1 * (1.f/NG);
  float m = ms[c];
  float var = s2 * (1.f/NG) - 2.f*m*mean*mean + m*m*mean*mean;
  float inv = rsqrtf(var + 1e-5f);
  float ww = w[c], bb = b[c];
  float pooled = 0.f;
  #pragma unroll
  for (int i = 0; i < NG; i++){
    float y = fmaf(ww * (v[i] - m*mean), inv, bb);
    pooled += (y > 0.f ? y : 0.f);
  }
  pooled *= (1.f/NG);
  float v0 = pooled * Wlin[c*2 + 0];
  float v1 = pooled * Wlin[c*2 + 1];
  #pragma unroll
  for (int o = 32; o; o >>= 1){ v0 += __shfl_down(v0, o); v1 += __shfl_down(v1, o); }
  if (c == 0){
    float o0 = v0 + blin[0], o1 = v1 + blin[1];
    if (is_f32(xus)){
      ((float*)out)[g*2 + 0] = o0;
      ((float*)out)[g*2 + 1] = o1;
    } else {
      ((__hip_bfloat16*)out)[g*2 + 0] = __float2bfloat16(o0);
      ((__hip_bfloat16*)out)[g*2 + 1] = __float2bfloat16(o1);
    }
  }
}

extern "C" void kernel_launch(void* const* d_in, const int* in_sizes, int n_in,
                              void* d_out, int out_size, void* d_ws, size_t ws_size,
                              hipStream_t stream){
  const int N = NNODES;
  const int E = in_sizes[1];

  const int* esrc = (const int*)d_in[1];
  const int* edst = (const int*)d_in[2];
  const unsigned short* xus = (const unsigned short*)d_in[0];

  // ---- workspace layout ----
  char* ws = (char*)d_ws;
  size_t cursor_b = 0;
  auto alloc = [&](size_t bytes)->char*{
    char* p = ws + cursor_b;
    cursor_b += (bytes + 255) & ~size_t(255);
    return p;
  };

  static const int convIdx[17] = {6,7,8,9,10, 13,14,15,16,17, 20,21,22,23,24, 25,26};
  CArgs ca;
  int cums[18]; cums[0] = 0;
  for (int i = 0; i < 17; i++){
    ca.p[i] = d_in[convIdx[i]];
    cums[i+1] = cums[i] + in_sizes[convIdx[i]];
  }
  memcpy(ca.cum, cums, sizeof(cums));
  int totalConv = cums[17];

  float* conv = (float*)alloc((size_t)totalConv * 4);
  const float* fw[17];
  for (int i = 0; i < 17; i++) fw[i] = conv + cums[i];
  // fw map: 0:att1 1:b1 2:gnw1 3:gnb1 4:gnm1
  //         5:att2 6:b2 7:gnw2 8:gnb2 9:gnm2
  //         10:att3 11:b3 12:gnw3 13:gnb3 14:gnm3 15:Wlin 16:blin

  __hip_bfloat16* XLbf  = (__hip_bfloat16*)alloc((size_t)N * CDIM * 2);
  __hip_bfloat16* XRbf  = (__hip_bfloat16*)alloc((size_t)N * CDIM * 2);
  __hip_bfloat16* OUTbf = (__hip_bfloat16*)alloc((size_t)N * CDIM * 2);   // attn out, pre-norm
  __hip_bfloat16* OUT3  = (__hip_bfloat16*)alloc((size_t)N * FDIM * 2);
  __hip_bfloat16* HBbf  = (__hip_bfloat16*)alloc((size_t)N * CDIM * 2);
  __hip_bfloat16* xbf   = (__hip_bfloat16*)alloc((size_t)N * GIN * 2);
  __hip_bfloat16* Wt[6];
  Wt[0] = (__hip_bfloat16*)alloc((size_t)CDIM * GIN * 2);
  Wt[1] = (__hip_bfloat16*)alloc((size_t)CDIM * GIN * 2);
  Wt[2] = (__hip_bfloat16*)alloc((size_t)CDIM * CDIM * 2);
  Wt[3] = (__hip_bfloat16*)alloc((size_t)CDIM * CDIM * 2);
  Wt[4] = (__hip_bfloat16*)alloc((size_t)CDIM * CDIM * 2);
  Wt[5] = (__hip_bfloat16*)alloc((size_t)CDIM * CDIM * 2);
  int* deg  = (int*)alloc((size_t)N * 4);
  int* off  = (int*)alloc((size_t)(N + 1) * 4);
  int* cur  = (int*)alloc((size_t)N * 4);
  int* srcs = (int*)alloc((size_t)E * 4);

  // ---- convert small vecs (+ zero deg), x->bf16 (+ count degrees), transpose weights ----
  k_convert<<<32, 256, 0, stream>>>(ca, xus, conv, totalConv, deg);
  k_xconv_count<<<2048, 256, 0, stream>>>(d_in[0], xbf, N * GIN, edst, E, deg);
  {
    TArgs ta;
    const void* Ws[6] = {d_in[4], d_in[5], d_in[11], d_in[12], d_in[18], d_in[19]};
    const int   Ks[6] = {GIN, GIN, CDIM, CDIM, CDIM, CDIM};
    for (int i = 0; i < 6; i++){ ta.W[i] = Ws[i]; ta.Wt[i] = Wt[i]; ta.K[i] = Ks[i]; }
    k_transpose_all<<<dim3(CDIM/32, CDIM/32, 6), dim3(32, 8), 0, stream>>>(ta, xus);
  }

  // ---- CSR by dst (payload = src) ----
  k_scan<<<1, 256, 0, stream>>>(deg, off, cur);
  k_fill<<<(E + 255)/256, 256, 0, stream>>>(esrc, edst, E, cur, srcs);

  // ---- 3 GATv2 + GraphNorm + ReLU layers ----
  const float* att_[3] = {fw[0],  fw[5],  fw[10]};
  const float* b_[3]   = {fw[1],  fw[6],  fw[11]};
  const float* gw_[3]  = {fw[2],  fw[7],  fw[12]};
  const float* gb_[3]  = {fw[3],  fw[8],  fw[13]};
  const float* gm_[3]  = {fw[4],  fw[9],  fw[14]};

  // layer 1
  k_gemm256<<<dim3(N/256, CDIM/256, 2), 512, 0, stream>>>(xbf, Wt[0], Wt[1], XLbf, XRbf, GIN);
  k_fused_attn<1><<<N/16, 256, 0, stream>>>(XLbf, XRbf, att_[0], off, srcs, b_[0], OUTbf);
  k_graphnorm_relu<<<NGRAPH, CDIM, 0, stream>>>(OUTbf, gw_[0], gb_[0], gm_[0], HBbf, CDIM);

  // layer 2
  k_gemm256<<<dim3(N/256, CDIM/256, 2), 512, 0, stream>>>(HBbf, Wt[2], Wt[3], XLbf, XRbf, CDIM);
  k_fused_attn<1><<<N/16, 256, 0, stream>>>(XLbf, XRbf, att_[1], off, srcs, b_[1], OUTbf);
  k_graphnorm_relu<<<NGRAPH, CDIM, 0, stream>>>(OUTbf, gw_[1], gb_[1], gm_[1], HBbf, CDIM);

  // layer 3
  k_gemm256<<<dim3(N/256, CDIM/256, 2), 512, 0, stream>>>(HBbf, Wt[4], Wt[5], XLbf, XRbf, CDIM);
  k_fused_attn<0><<<N/16, 256, 0, stream>>>(XLbf, XRbf, att_[2], off, srcs, b_[2], OUT3);
  k_norm_pool<<<NGRAPH, 64, 0, stream>>>(OUT3, gw_[2], gb_[2], gm_[2], fw[15], fw[16], d_out, xus);
}

// Round 10
// 321.817 us; speedup vs baseline: 1.0133x; 1.0133x over previous
//
#include <hip/hip_runtime.h>
#include <hip/hip_bf16.h>
#include <stdint.h>
#include <string.h>

#define NNODES 16384
#define GIN 256      // input feature dim
#define NG 64        // nodes per graph (N/G)
#define NGRAPH 256
#define FDIM 64      // per-head out dim
#define CDIM 512     // H*F

typedef __attribute__((ext_vector_type(8))) short bf16x8;
typedef __attribute__((ext_vector_type(4))) float f32x4;
typedef __attribute__((ext_vector_type(2))) float f32x2;

__device__ __forceinline__ float bf2f(unsigned short u){
  union { unsigned int i; float f; } w; w.i = ((unsigned int)u) << 16; return w.f;
}

// unpack two bf16 packed in a uint to an f32 pair
__device__ __forceinline__ f32x2 unpk2(unsigned int u){
  union { unsigned int i; float f; } a, b;
  a.i = u << 16; b.i = u & 0xffff0000u;
  return (f32x2){a.f, b.f};
}

// CDNA full-rate packed f32 VALU (VOP3P) — one instruction covers 2 channels
__device__ __forceinline__ f32x2 pk_add(f32x2 a, f32x2 b){
  f32x2 d; asm("v_pk_add_f32 %0, %1, %2" : "=v"(d) : "v"(a), "v"(b)); return d;
}
__device__ __forceinline__ f32x2 pk_mul(f32x2 a, f32x2 b){
  f32x2 d; asm("v_pk_mul_f32 %0, %1, %2" : "=v"(d) : "v"(a), "v"(b)); return d;
}
__device__ __forceinline__ f32x2 pk_fma(f32x2 a, f32x2 b, f32x2 c){
  f32x2 d; asm("v_pk_fma_f32 %0, %1, %2, %3" : "=v"(d) : "v"(a), "v"(b), "v"(c)); return d;
}

union PK8 { __hip_bfloat16 h[8]; uint4 v; };

__device__ __forceinline__ void async16(const void* g, void* l){
  __builtin_amdgcn_global_load_lds(
      (const __attribute__((address_space(1))) unsigned int*)g,
      (__attribute__((address_space(3))) unsigned int*)l, 16, 0, 0);
}

// ---------- local dtype detection ----------
__device__ __forceinline__ int is_f32(const unsigned short* __restrict__ x){
  int bad = 0;
  #pragma unroll
  for (int j = 0; j < 64; j++){
    float f = bf2f(x[j*4]);
    if (!(fabsf(f) < 1e4f)) bad++;
  }
  return bad > 4;
}

// ---------- small-vector conversion to fp32 (17 segments) + deg zeroing ----------
struct CArgs {
  const void* p[17];
  int cum[18];
};

__global__ void k_convert(CArgs a, const unsigned short* __restrict__ x,
                          float* __restrict__ dst, int total, int* __restrict__ deg){
  int isf32 = is_f32(x);
  int totAll = total + NNODES;
  for (int idx = blockIdx.x*blockDim.x + threadIdx.x; idx < totAll; idx += gridDim.x*blockDim.x){
    if (idx >= total){ deg[idx - total] = 0; continue; }
    int seg = 0;
    while (idx >= a.cum[seg+1]) seg++;
    int off = idx - a.cum[seg];
    float v;
    if (isf32) v = ((const float*)a.p[seg])[off];
    else       v = bf2f(((const unsigned short*)a.p[seg])[off]);
    dst[idx] = v;
  }
}

// ---------- x -> bf16 + edge degree count (deg pre-zeroed by k_convert) ----------
__global__ void k_xconv_count(const void* __restrict__ xin,
                              __hip_bfloat16* __restrict__ xbf, int total,
                              const int* __restrict__ edst, int E, int* __restrict__ deg){
  int isf32 = is_f32((const unsigned short*)xin);
  for (int idx = blockIdx.x*blockDim.x + threadIdx.x; idx < total; idx += gridDim.x*blockDim.x){
    float v;
    if (isf32) v = ((const float*)xin)[idx];
    else       v = bf2f(((const unsigned short*)xin)[idx]);
    xbf[idx] = __float2bfloat16(v);
  }
  for (int e = blockIdx.x*blockDim.x + threadIdx.x; e < E; e += gridDim.x*blockDim.x)
    atomicAdd(&deg[edst[e]], 1);
}

// ---------- merged transpose from RAW weights ----------
struct TArgs {
  const void* W[6];
  __hip_bfloat16* Wt[6];
  int K[6];
};

__global__ void k_transpose_all(TArgs t, const unsigned short* __restrict__ x){
  int isf32 = is_f32(x);
  int seg = blockIdx.z;
  int K = t.K[seg];
  int n0 = blockIdx.x*32, k0 = blockIdx.y*32;
  if (k0 >= K) return;
  const void* W = t.W[seg];
  __hip_bfloat16* Wt = t.Wt[seg];
  __shared__ float tl[32][33];
  for (int r = threadIdx.y; r < 32; r += 8){
    size_t idx = (size_t)(k0 + r)*CDIM + n0 + threadIdx.x;
    tl[r][threadIdx.x] = isf32 ? ((const float*)W)[idx] : bf2f(((const unsigned short*)W)[idx]);
  }
  __syncthreads();
  for (int r = threadIdx.y; r < 32; r += 8)
    Wt[(size_t)(n0 + r)*K + k0 + threadIdx.x] = __float2bfloat16(tl[threadIdx.x][r]);
}

// ---------- CSR build (by dst), payload = src node ----------
__global__ void k_scan(const int* __restrict__ deg, int* __restrict__ off, int* __restrict__ cur){
  __shared__ int ss[256];
  int t = threadIdx.x;
  const int4* d4 = (const int4*)(deg + t*64);
  int4 buf[16];
  int s = 0;
  #pragma unroll
  for (int j = 0; j < 16; j++){
    buf[j] = d4[j];
    s += buf[j].x + buf[j].y + buf[j].z + buf[j].w;
  }
  ss[t] = s;
  __syncthreads();
  for (int o = 1; o < 256; o <<= 1){
    int v = 0;
    if (t >= o) v = ss[t - o];
    __syncthreads();
    if (t >= o) ss[t] += v;
    __syncthreads();
  }
  int run = ss[t] - s;  // exclusive prefix
  int4* o4 = (int4*)(off + t*64);
  int4* c4 = (int4*)(cur + t*64);
  #pragma unroll
  for (int j = 0; j < 16; j++){
    int4 v;
    v.x = run; run += buf[j].x;
    v.y = run; run += buf[j].y;
    v.z = run; run += buf[j].z;
    v.w = run; run += buf[j].w;
    o4[j] = v; c4[j] = v;
  }
  if (t == 255) off[NNODES] = run;
}

__global__ void k_fill(const int* __restrict__ esrc, const int* __restrict__ edst, int E,
                       int* __restrict__ cur, int* __restrict__ srcs){
  int e = blockIdx.x*blockDim.x + threadIdx.x;
  if (e < E){
    int pos = atomicAdd(&cur[edst[e]], 1);
    srcs[pos] = esrc[e];
  }
}

// ---------- bf16 MFMA GEMM, 256x256 tile, BK=64, 8-wave 8-phase counted-vmcnt schedule ----------
// (verified; <=15us marginal/launch at K=512 per round-6 REPS ablation top-5 bound)
// NOTE: tail-wrap garbage stages are LOAD-BEARING for the vmcnt(4) ledger — do not remove.
#define GBAR  do { asm volatile("" ::: "memory"); __builtin_amdgcn_s_barrier(); asm volatile("" ::: "memory"); } while(0)

#define PHASE(BUF, MH, NH, LA, LB, SBUF, SISB, SUNIT, ST, DOVM)                                   \
  { if (LA){ _Pragma("unroll") for (int ko_=0;ko_<2;ko_++)                                        \
               _Pragma("unroll") for (int ii_=0;ii_<4;ii_++) Afr[ko_][ii_]=rdA(BUF,MH,ii_,ko_); } \
    if (LB){ _Pragma("unroll") for (int ko_=0;ko_<2;ko_++)                                        \
               _Pragma("unroll") for (int jj_=0;jj_<2;jj_++) Bfr[ko_][jj_]=rdB(BUF,NH,jj_,ko_); } \
    stage(SBUF,SISB,SUNIT,ST);                                                                    \
    if (DOVM) asm volatile("s_waitcnt vmcnt(4)" ::: "memory");                                    \
    GBAR;                                                                                         \
    __builtin_amdgcn_s_setprio(1);                                                                \
    _Pragma("unroll") for (int ii_=0;ii_<4;ii_++)                                                 \
      _Pragma("unroll") for (int jj_=0;jj_<2;jj_++)                                               \
        _Pragma("unroll") for (int ko_=0;ko_<2;ko_++)                                             \
          acc[(MH)*4+ii_][(NH)*2+jj_] = __builtin_amdgcn_mfma_f32_16x16x32_bf16(                  \
              Afr[ko_][ii_], Bfr[ko_][jj_], acc[(MH)*4+ii_][(NH)*2+jj_], 0, 0, 0);                \
    __builtin_amdgcn_s_setprio(0);                                                                \
    GBAR; }

__global__ __launch_bounds__(512, 2) void k_gemm256(
    const __hip_bfloat16* __restrict__ A,
    const __hip_bfloat16* __restrict__ Wtl, const __hip_bfloat16* __restrict__ Wtr,
    __hip_bfloat16* __restrict__ Cl, __hip_bfloat16* __restrict__ Cr, int K){
  const __hip_bfloat16* Wt = blockIdx.z ? Wtr : Wtl;
  __hip_bfloat16*       C  = blockIdx.z ? Cr  : Cl;
  __shared__ __align__(128) char lds[131072];   // A: [0,64K)  B: [64K,128K)
  const int tid = threadIdx.x;
  const int w = tid >> 6, lane = tid & 63;
  const int wm = w >> 2, wn = w & 3;
  const int l16 = lane & 15, c4 = lane >> 4;
  const int row0 = blockIdx.x * 256, col0 = blockIdx.y * 256;
  const int NT = K >> 6;

  f32x4 acc[8][4];
  bf16x8 Afr[2][4];   // [ko][ii]  current mh
  bf16x8 Bfr[2][2];   // [ko][jj]  current nh

  const __hip_bfloat16* Ag = A  + (size_t)row0 * K;
  const __hip_bfloat16* Bg = Wt + (size_t)col0 * K;

  auto stage = [&](int buf, int isB, int unit, int t){
    int k0 = (t < NT ? t : t - NT) << 6;        // tail wrap -> dead-region garbage stage
    #pragma unroll
    for (int j = 0; j < 2; j++){
      int u0 = (w*2 + j) * 8;                   // wave-uniform
      int uidx = u0 + (lane >> 3);              // 0..127 within unit
      int row, rs;
      if (!isB){ row = (uidx & 63) | ((uidx & 64) << 1) | (unit << 6);
                 rs  = (u0   & 63) | ((u0   & 64) << 1) | (unit << 6); }
      else     { row = ((uidx & 96) << 1) | (uidx & 31) | (unit << 5);
                 rs  = ((u0   & 96) << 1) | (u0   & 31) | (unit << 5); }
      int chunk = (lane & 7) ^ (uidx & 7);      // inverse-swizzled global source
      const __hip_bfloat16* gp = (isB ? Bg : Ag) + (size_t)row * K + k0 + chunk * 8;
      async16(gp, lds + (isB ? 65536 : 0) + buf * 32768 + rs * 128);
    }
  };

  auto rdA = [&](int buf, int mh, int ii, int ko)->bf16x8{
    int row = wm*128 + mh*64 + ii*16 + l16;
    int chunk = ((ko<<2) + c4) ^ (l16 & 7);
    return *(const bf16x8*)(lds + buf*32768 + row*128 + chunk*16);
  };
  auto rdB = [&](int buf, int nh, int jj, int ko)->bf16x8{
    int row = wn*64 + nh*32 + jj*16 + l16;
    int chunk = ((ko<<2) + c4) ^ (l16 & 7);
    return *(const bf16x8*)(lds + 65536 + buf*32768 + row*128 + chunk*16);
  };

  #pragma unroll
  for (int i = 0; i < 8; i++)
    #pragma unroll
    for (int j = 0; j < 4; j++) acc[i][j] = (f32x4){0.f,0.f,0.f,0.f};

  // prologue: full tile0 + A(1)u0 + B(1)u1, allow last 2 units in flight
  stage(0,0,0,0); stage(0,1,1,0); stage(0,0,1,0); stage(0,1,0,0);
  stage(1,0,0,1); stage(1,1,1,1);
  asm volatile("s_waitcnt vmcnt(4)" ::: "memory");
  GBAR;

  for (int t = 0; t < NT; t += 2){
    PHASE(0, 0, 0, 1, 1, 1, 0, 1, t+1, 0)   // ph1: stage A(t+1)u1 -> buf1
    PHASE(0, 0, 1, 0, 1, 1, 1, 0, t+1, 0)   // ph2: stage B(t+1)u0 -> buf1
    PHASE(0, 1, 1, 1, 0, 0, 0, 0, t+2, 0)   // ph3: stage A(t+2)u0 -> buf0
    PHASE(0, 1, 0, 0, 1, 0, 1, 1, t+2, 1)   // ph4: stage B(t+2)u1 -> buf0, vmcnt(4)
    PHASE(1, 0, 0, 1, 1, 0, 0, 1, t+2, 0)   // ph5: stage A(t+2)u1 -> buf0
    PHASE(1, 0, 1, 0, 1, 0, 1, 0, t+2, 0)   // ph6: stage B(t+2)u0 -> buf0
    PHASE(1, 1, 1, 1, 0, 1, 0, 0, t+3, 0)   // ph7: stage A(t+3)u0 -> buf1
    PHASE(1, 1, 0, 0, 1, 1, 1, 1, t+3, 1)   // ph8: stage B(t+3)u1 -> buf1, vmcnt(4)
  }

  // drain wrapped garbage stages before reusing LDS as C-staging tile
  asm volatile("s_waitcnt vmcnt(0)" ::: "memory");
  GBAR;
  {
    __hip_bfloat16* ct = (__hip_bfloat16*)lds;   // [256][256] bf16 = 128 KiB
    #pragma unroll
    for (int i = 0; i < 8; i++)
      #pragma unroll
      for (int j = 0; j < 4; j++)
        #pragma unroll
        for (int r = 0; r < 4; r++){
          int rl = wm*128 + i*16 + c4*4 + r;
          int cl = wn*64  + j*16 + l16;
          ct[rl*256 + cl] = __float2bfloat16(acc[i][j][r]);
        }
  }
  // ds_write -> barrier -> ds_read requires the writer's lgkmcnt(0) (ISA §8)
  asm volatile("s_waitcnt lgkmcnt(0)" ::: "memory");
  GBAR;
  #pragma unroll
  for (int s = 0; s < 16; s++){
    int seg = s*512 + tid;            // 8192 x 16B
    int rl = seg >> 5, ch = seg & 31;
    uint4 v = *(const uint4*)(lds + rl*512 + ch*16);
    *(uint4*)((char*)(C + (size_t)(row0 + rl)*CDIM + col0) + ch*16) = v;
  }
}

// ---------- fused GATv2 edge phase: 4 waves/block, ONE node/wave, packed-f32 VALU ----------
// Config matrix (r6/r8/r9 ablations): this is the untested cell combining the two
// proven wins — packed VALU + __expf (r8: real gain) at full occupancy (grid N/4 =
// 4096 blocks = 16 blocks/CU available, VGPR-capped ~28 waves/CU; r9's N/16 grid
// self-capped at 16 waves/CU and serialized 4 nodes per wave — regressed).
template<int CONCAT>
__global__ __launch_bounds__(256) void k_fused_attn(
    const __hip_bfloat16* __restrict__ XL, const __hip_bfloat16* __restrict__ XR,
    const float* __restrict__ att,
    const int* __restrict__ off, const int* __restrict__ srcs,
    const float* __restrict__ bias, __hip_bfloat16* __restrict__ OUT){
  int wave = threadIdx.x >> 6, lane = threadIdx.x & 63;
  int d = blockIdx.x * 4 + wave;

  const f32x2* atp = (const f32x2*)(att + lane*8);
  f32x2 at2[4] = {atp[0], atp[1], atp[2], atp[3]};
  const f32x2 c02 = {0.2f, 0.2f};
  const float4* bp = (const float4*)(bias + (CONCAT ? lane*8 : (lane & 7)*8));
  float4 b0v = bp[0], b1v = bp[1];
  float bb[8] = {b0v.x, b0v.y, b0v.z, b0v.w, b1v.x, b1v.y, b1v.z, b1v.w};

  uint4 xru = *(const uint4*)((const char*)XR + ((size_t)d*CDIM + lane*8)*2);
  f32x2 xr2[4] = {unpk2(xru.x), unpk2(xru.y), unpk2(xru.z), unpk2(xru.w)};

  f32x2 acc2[4];
  #pragma unroll
  for (int k = 0; k < 4; k++) acc2[k] = (f32x2){0.f, 0.f};
  float den = 0.f;

  int beg = off[d], end = off[d+1];   // end > beg guaranteed (self-loops appended)

  uint4 rwA[4], rwB[4];

  auto ldgth = [&](int i, uint4* rw){
    int n = end - i;                       // wave-uniform, >= 1
    int s0 = srcs[i];
    int s1 = n > 1 ? srcs[i+1] : s0;
    int s2 = n > 2 ? srcs[i+2] : s0;
    int s3 = n > 3 ? srcs[i+3] : s0;
    rw[0] = *(const uint4*)((const char*)XL + ((size_t)s0*CDIM + lane*8)*2);
    rw[1] = *(const uint4*)((const char*)XL + ((size_t)s1*CDIM + lane*8)*2);
    rw[2] = *(const uint4*)((const char*)XL + ((size_t)s2*CDIM + lane*8)*2);
    rw[3] = *(const uint4*)((const char*)XL + ((size_t)s3*CDIM + lane*8)*2);
  };

  auto compute = [&](const uint4* rw, int n){
    #pragma unroll
    for (int e = 0; e < 4; e++){
      if (e < n){                          // wave-uniform branch
        f32x2 xv2[4] = {unpk2(rw[e].x), unpk2(rw[e].y), unpk2(rw[e].z), unpk2(rw[e].w)};
        f32x2 v2 = (f32x2){0.f, 0.f};
        #pragma unroll
        for (int k = 0; k < 4; k++){
          f32x2 m2 = pk_add(xv2[k], xr2[k]);
          f32x2 t2 = pk_mul(m2, c02);
          f32x2 l2 = (f32x2){fmaxf(m2[0], t2[0]), fmaxf(m2[1], t2[1])};  // leaky
          v2 = pk_fma(l2, at2[k], v2);
        }
        float v = v2[0] + v2[1];
        v += __shfl_xor(v, 1); v += __shfl_xor(v, 2); v += __shfl_xor(v, 4);
        float p = __expf(v);
        den += p;
        f32x2 p2 = (f32x2){p, p};
        #pragma unroll
        for (int k = 0; k < 4; k++) acc2[k] = pk_fma(p2, xv2[k], acc2[k]);
      }
    }
  };

  ldgth(beg, rwA);
  int i = beg;
  while (true){
    int iB = i + 4;
    if (iB >= end){ compute(rwA, end - i); break; }
    ldgth(iB, rwB);                        // issue next group before waiting on rwA
    compute(rwA, 4);
    int iA = iB + 4;
    if (iA >= end){ compute(rwB, end - iB); break; }
    ldgth(iA, rwA);
    compute(rwB, 4);
    i = iA;
  }

  float inv = 1.f / (den + 1e-16f);

  if (CONCAT){
    PK8 pk;
    #pragma unroll
    for (int k = 0; k < 4; k++){
      pk.h[2*k]   = __float2bfloat16(acc2[k][0]*inv + bb[2*k]);
      pk.h[2*k+1] = __float2bfloat16(acc2[k][1]*inv + bb[2*k+1]);
    }
    *(uint4*)((char*)OUT + ((size_t)d*CDIM + lane*8)*2) = pk.v;
  } else {
    float r[8];
    #pragma unroll
    for (int k = 0; k < 4; k++){ r[2*k] = acc2[k][0]*inv; r[2*k+1] = acc2[k][1]*inv; }
    #pragma unroll
    for (int o = 8; o < 64; o <<= 1)
      #pragma unroll
      for (int j = 0; j < 8; j++) r[j] += __shfl_xor(r[j], o);
    if (lane < 8){
      PK8 pk;
      #pragma unroll
      for (int j = 0; j < 8; j++)
        pk.h[j] = __float2bfloat16(r[j]*0.125f + bb[j]);
      *(uint4*)((char*)OUT + ((size_t)d*FDIM + lane*8)*2) = pk.v;
    }
  }
}

// ---------- GraphNorm + ReLU (layers 1-2) ----------
__global__ void k_graphnorm_relu(const __hip_bfloat16* __restrict__ X, const float* __restrict__ w,
    const float* __restrict__ b, const float* __restrict__ ms,
    __hip_bfloat16* __restrict__ Y, int C){
  int g = blockIdx.x;
  int c = threadIdx.x;
  const __hip_bfloat16* xg = X + (size_t)g * NG * C + c;
  __hip_bfloat16* yg = Y + (size_t)g * NG * C + c;
  float v[NG];
  float s1 = 0.f, s2 = 0.f;
  #pragma unroll
  for (int i = 0; i < NG; i++){
    v[i] = __bfloat162float(xg[(size_t)i*C]);
    s1 += v[i]; s2 += v[i]*v[i];
  }
  float mean = s1 * (1.f/NG);
  float m = ms[c];
  float var = s2 * (1.f/NG) - 2.f*m*mean*mean + m*m*mean*mean;
  float inv = rsqrtf(var + 1e-5f);
  float ww = w[c], bb = b[c];
  #pragma unroll
  for (int i = 0; i < NG; i++){
    float y = fmaf(ww * (v[i] - m*mean), inv, bb);
    yg[(size_t)i*C] = __float2bfloat16(y > 0.f ? y : 0.f);
  }
}

// ---------- layer 3: GraphNorm + ReLU + mean-pool + linear [64->2], fused ----------
__global__ void k_norm_pool(const __hip_bfloat16* __restrict__ X, const float* __restrict__ w,
    const float* __restrict__ b, const float* __restrict__ ms,
    const float* __restrict__ Wlin, const float* __restrict__ blin,
    void* out, const unsigned short* __restrict__ xus){
  int g = blockIdx.x, c = threadIdx.x;  // 64 threads, c = channel
  const __hip_bfloat16* xg = X + (size_t)g * NG * FDIM + c;
  float v[NG];
  float s1 = 0.f, s2 = 0.f;
  #pragma unroll
  for (int i = 0; i < NG; i++){
    v[i] = __bfloat162float(xg[(size_t)i*FDIM]);
    s1 += v[i]; s2 += v[i]*v[i];
  }
  float mean = s1 * (1.f/NG);
  float m = ms[c];
  float var = s2 * (1.f/NG) - 2.f*m*mean*mean + m*m*mean*mean;
  float inv = rsqrtf(var + 1e-5f);
  float ww = w[c], bb = b[c];
  float pooled = 0.f;
  #pragma unroll
  for (int i = 0; i < NG; i++){
    float y = fmaf(ww * (v[i] - m*mean), inv, bb);
    pooled += (y > 0.f ? y : 0.f);
  }
  pooled *= (1.f/NG);
  float v0 = pooled * Wlin[c*2 + 0];
  float v1 = pooled * Wlin[c*2 + 1];
  #pragma unroll
  for (int o = 32; o; o >>= 1){ v0 += __shfl_down(v0, o); v1 += __shfl_down(v1, o); }
  if (c == 0){
    float o0 = v0 + blin[0], o1 = v1 + blin[1];
    if (is_f32(xus)){
      ((float*)out)[g*2 + 0] = o0;
      ((float*)out)[g*2 + 1] = o1;
    } else {
      ((__hip_bfloat16*)out)[g*2 + 0] = __float2bfloat16(o0);
      ((__hip_bfloat16*)out)[g*2 + 1] = __float2bfloat16(o1);
    }
  }
}

extern "C" void kernel_launch(void* const* d_in, const int* in_sizes, int n_in,
                              void* d_out, int out_size, void* d_ws, size_t ws_size,
                              hipStream_t stream){
  const int N = NNODES;
  const int E = in_sizes[1];

  const int* esrc = (const int*)d_in[1];
  const int* edst = (const int*)d_in[2];
  const unsigned short* xus = (const unsigned short*)d_in[0];

  // ---- workspace layout ----
  char* ws = (char*)d_ws;
  size_t cursor_b = 0;
  auto alloc = [&](size_t bytes)->char*{
    char* p = ws + cursor_b;
    cursor_b += (bytes + 255) & ~size_t(255);
    return p;
  };

  static const int convIdx[17] = {6,7,8,9,10, 13,14,15,16,17, 20,21,22,23,24, 25,26};
  CArgs ca;
  int cums[18]; cums[0] = 0;
  for (int i = 0; i < 17; i++){
    ca.p[i] = d_in[convIdx[i]];
    cums[i+1] = cums[i] + in_sizes[convIdx[i]];
  }
  memcpy(ca.cum, cums, sizeof(cums));
  int totalConv = cums[17];

  float* conv = (float*)alloc((size_t)totalConv * 4);
  const float* fw[17];
  for (int i = 0; i < 17; i++) fw[i] = conv + cums[i];
  // fw map: 0:att1 1:b1 2:gnw1 3:gnb1 4:gnm1
  //         5:att2 6:b2 7:gnw2 8:gnb2 9:gnm2
  //         10:att3 11:b3 12:gnw3 13:gnb3 14:gnm3 15:Wlin 16:blin

  __hip_bfloat16* XLbf  = (__hip_bfloat16*)alloc((size_t)N * CDIM * 2);
  __hip_bfloat16* XRbf  = (__hip_bfloat16*)alloc((size_t)N * CDIM * 2);
  __hip_bfloat16* OUTbf = (__hip_bfloat16*)alloc((size_t)N * CDIM * 2);   // attn out, pre-norm
  __hip_bfloat16* OUT3  = (__hip_bfloat16*)alloc((size_t)N * FDIM * 2);
  __hip_bfloat16* HBbf  = (__hip_bfloat16*)alloc((size_t)N * CDIM * 2);
  __hip_bfloat16* xbf   = (__hip_bfloat16*)alloc((size_t)N * GIN * 2);
  __hip_bfloat16* Wt[6];
  Wt[0] = (__hip_bfloat16*)alloc((size_t)CDIM * GIN * 2);
  Wt[1] = (__hip_bfloat16*)alloc((size_t)CDIM * GIN * 2);
  Wt[2] = (__hip_bfloat16*)alloc((size_t)CDIM * CDIM * 2);
  Wt[3] = (__hip_bfloat16*)alloc((size_t)CDIM * CDIM * 2);
  Wt[4] = (__hip_bfloat16*)alloc((size_t)CDIM * CDIM * 2);
  Wt[5] = (__hip_bfloat16*)alloc((size_t)CDIM * CDIM * 2);
  int* deg  = (int*)alloc((size_t)N * 4);
  int* off  = (int*)alloc((size_t)(N + 1) * 4);
  int* cur  = (int*)alloc((size_t)N * 4);
  int* srcs = (int*)alloc((size_t)E * 4);

  // ---- convert small vecs (+ zero deg), x->bf16 (+ count degrees), transpose weights ----
  k_convert<<<32, 256, 0, stream>>>(ca, xus, conv, totalConv, deg);
  k_xconv_count<<<2048, 256, 0, stream>>>(d_in[0], xbf, N * GIN, edst, E, deg);
  {
    TArgs ta;
    const void* Ws[6] = {d_in[4], d_in[5], d_in[11], d_in[12], d_in[18], d_in[19]};
    const int   Ks[6] = {GIN, GIN, CDIM, CDIM, CDIM, CDIM};
    for (int i = 0; i < 6; i++){ ta.W[i] = Ws[i]; ta.Wt[i] = Wt[i]; ta.K[i] = Ks[i]; }
    k_transpose_all<<<dim3(CDIM/32, CDIM/32, 6), dim3(32, 8), 0, stream>>>(ta, xus);
  }

  // ---- CSR by dst (payload = src) ----
  k_scan<<<1, 256, 0, stream>>>(deg, off, cur);
  k_fill<<<(E + 255)/256, 256, 0, stream>>>(esrc, edst, E, cur, srcs);

  // ---- 3 GATv2 + GraphNorm + ReLU layers ----
  const float* att_[3] = {fw[0],  fw[5],  fw[10]};
  const float* b_[3]   = {fw[1],  fw[6],  fw[11]};
  const float* gw_[3]  = {fw[2],  fw[7],  fw[12]};
  const float* gb_[3]  = {fw[3],  fw[8],  fw[13]};
  const float* gm_[3]  = {fw[4],  fw[9],  fw[14]};

  // layer 1
  k_gemm256<<<dim3(N/256, CDIM/256, 2), 512, 0, stream>>>(xbf, Wt[0], Wt[1], XLbf, XRbf, GIN);
  k_fused_attn<1><<<N/4, 256, 0, stream>>>(XLbf, XRbf, att_[0], off, srcs, b_[0], OUTbf);
  k_graphnorm_relu<<<NGRAPH, CDIM, 0, stream>>>(OUTbf, gw_[0], gb_[0], gm_[0], HBbf, CDIM);

  // layer 2
  k_gemm256<<<dim3(N/256, CDIM/256, 2), 512, 0, stream>>>(HBbf, Wt[2], Wt[3], XLbf, XRbf, CDIM);
  k_fused_attn<1><<<N/4, 256, 0, stream>>>(XLbf, XRbf, att_[1], off, srcs, b_[1], OUTbf);
  k_graphnorm_relu<<<NGRAPH, CDIM, 0, stream>>>(OUTbf, gw_[1], gb_[1], gm_[1], HBbf, CDIM);

  // layer 3
  k_gemm256<<<dim3(N/256, CDIM/256, 2), 512, 0, stream>>>(HBbf, Wt[4], Wt[5], XLbf, XRbf, CDIM);
  k_fused_attn<0><<<N/4, 256, 0, stream>>>(XLbf, XRbf, att_[2], off, srcs, b_[2], OUT3);
  k_norm_pool<<<NGRAPH, 64, 0, stream>>>(OUT3, gw_[2], gb_[2], gm_[2], fw[15], fw[16], d_out, xus);
}

// Round 11
// 320.248 us; speedup vs baseline: 1.0182x; 1.0049x over previous
//
#include <hip/hip_runtime.h>
#include <hip/hip_bf16.h>
#include <stdint.h>
#include <string.h>

#define NNODES 16384
#define GIN 256      // input feature dim
#define NG 64        // nodes per graph (N/G)
#define NGRAPH 256
#define FDIM 64      // per-head out dim
#define CDIM 512     // H*F

typedef __attribute__((ext_vector_type(8))) short bf16x8;
typedef __attribute__((ext_vector_type(4))) float f32x4;
typedef __attribute__((ext_vector_type(2))) float f32x2;

__device__ __forceinline__ float bf2f(unsigned short u){
  union { unsigned int i; float f; } w; w.i = ((unsigned int)u) << 16; return w.f;
}

// unpack two bf16 packed in a uint to an f32 pair
__device__ __forceinline__ f32x2 unpk2(unsigned int u){
  union { unsigned int i; float f; } a, b;
  a.i = u << 16; b.i = u & 0xffff0000u;
  return (f32x2){a.f, b.f};
}

// CDNA full-rate packed f32 VALU (VOP3P) — one instruction covers 2 channels
__device__ __forceinline__ f32x2 pk_add(f32x2 a, f32x2 b){
  f32x2 d; asm("v_pk_add_f32 %0, %1, %2" : "=v"(d) : "v"(a), "v"(b)); return d;
}
__device__ __forceinline__ f32x2 pk_mul(f32x2 a, f32x2 b){
  f32x2 d; asm("v_pk_mul_f32 %0, %1, %2" : "=v"(d) : "v"(a), "v"(b)); return d;
}
__device__ __forceinline__ f32x2 pk_fma(f32x2 a, f32x2 b, f32x2 c){
  f32x2 d; asm("v_pk_fma_f32 %0, %1, %2, %3" : "=v"(d) : "v"(a), "v"(b), "v"(c)); return d;
}

union PK8 { __hip_bfloat16 h[8]; uint4 v; };

__device__ __forceinline__ void async16(const void* g, void* l){
  __builtin_amdgcn_global_load_lds(
      (const __attribute__((address_space(1))) unsigned int*)g,
      (__attribute__((address_space(3))) unsigned int*)l, 16, 0, 0);
}

// ---------- local dtype detection ----------
__device__ __forceinline__ int is_f32(const unsigned short* __restrict__ x){
  int bad = 0;
  #pragma unroll
  for (int j = 0; j < 64; j++){
    float f = bf2f(x[j*4]);
    if (!(fabsf(f) < 1e4f)) bad++;
  }
  return bad > 4;
}

// ---------- small-vector conversion to fp32 (17 segments) + deg zeroing ----------
struct CArgs {
  const void* p[17];
  int cum[18];
};

__global__ void k_convert(CArgs a, const unsigned short* __restrict__ x,
                          float* __restrict__ dst, int total, int* __restrict__ deg){
  int isf32 = is_f32(x);
  int totAll = total + NNODES;
  for (int idx = blockIdx.x*blockDim.x + threadIdx.x; idx < totAll; idx += gridDim.x*blockDim.x){
    if (idx >= total){ deg[idx - total] = 0; continue; }
    int seg = 0;
    while (idx >= a.cum[seg+1]) seg++;
    int off = idx - a.cum[seg];
    float v;
    if (isf32) v = ((const float*)a.p[seg])[off];
    else       v = bf2f(((const unsigned short*)a.p[seg])[off]);
    dst[idx] = v;
  }
}

// ---------- x -> bf16 + edge degree count (deg pre-zeroed by k_convert) ----------
__global__ void k_xconv_count(const void* __restrict__ xin,
                              __hip_bfloat16* __restrict__ xbf, int total,
                              const int* __restrict__ edst, int E, int* __restrict__ deg){
  int isf32 = is_f32((const unsigned short*)xin);
  for (int idx = blockIdx.x*blockDim.x + threadIdx.x; idx < total; idx += gridDim.x*blockDim.x){
    float v;
    if (isf32) v = ((const float*)xin)[idx];
    else       v = bf2f(((const unsigned short*)xin)[idx]);
    xbf[idx] = __float2bfloat16(v);
  }
  for (int e = blockIdx.x*blockDim.x + threadIdx.x; e < E; e += gridDim.x*blockDim.x)
    atomicAdd(&deg[edst[e]], 1);
}

// ---------- merged transpose from RAW weights ----------
struct TArgs {
  const void* W[6];
  __hip_bfloat16* Wt[6];
  int K[6];
};

__global__ void k_transpose_all(TArgs t, const unsigned short* __restrict__ x){
  int isf32 = is_f32(x);
  int seg = blockIdx.z;
  int K = t.K[seg];
  int n0 = blockIdx.x*32, k0 = blockIdx.y*32;
  if (k0 >= K) return;
  const void* W = t.W[seg];
  __hip_bfloat16* Wt = t.Wt[seg];
  __shared__ float tl[32][33];
  for (int r = threadIdx.y; r < 32; r += 8){
    size_t idx = (size_t)(k0 + r)*CDIM + n0 + threadIdx.x;
    tl[r][threadIdx.x] = isf32 ? ((const float*)W)[idx] : bf2f(((const unsigned short*)W)[idx]);
  }
  __syncthreads();
  for (int r = threadIdx.y; r < 32; r += 8)
    Wt[(size_t)(n0 + r)*K + k0 + threadIdx.x] = __float2bfloat16(tl[threadIdx.x][r]);
}

// ---------- CSR build (by dst), payload = src node ----------
__global__ void k_scan(const int* __restrict__ deg, int* __restrict__ off, int* __restrict__ cur){
  __shared__ int ss[256];
  int t = threadIdx.x;
  const int4* d4 = (const int4*)(deg + t*64);
  int4 buf[16];
  int s = 0;
  #pragma unroll
  for (int j = 0; j < 16; j++){
    buf[j] = d4[j];
    s += buf[j].x + buf[j].y + buf[j].z + buf[j].w;
  }
  ss[t] = s;
  __syncthreads();
  for (int o = 1; o < 256; o <<= 1){
    int v = 0;
    if (t >= o) v = ss[t - o];
    __syncthreads();
    if (t >= o) ss[t] += v;
    __syncthreads();
  }
  int run = ss[t] - s;  // exclusive prefix
  int4* o4 = (int4*)(off + t*64);
  int4* c4 = (int4*)(cur + t*64);
  #pragma unroll
  for (int j = 0; j < 16; j++){
    int4 v;
    v.x = run; run += buf[j].x;
    v.y = run; run += buf[j].y;
    v.z = run; run += buf[j].z;
    v.w = run; run += buf[j].w;
    o4[j] = v; c4[j] = v;
  }
  if (t == 255) off[NNODES] = run;
}

__global__ void k_fill(const int* __restrict__ esrc, const int* __restrict__ edst, int E,
                       int* __restrict__ cur, int* __restrict__ srcs){
  int e = blockIdx.x*blockDim.x + threadIdx.x;
  if (e < E){
    int pos = atomicAdd(&cur[edst[e]], 1);
    srcs[pos] = esrc[e];
  }
}

// ---------- bf16 MFMA GEMM, 256x256 tile, BK=64, 8-wave 8-phase counted-vmcnt schedule ----------
// (verified; <=15us marginal/launch at K=512 per round-6 REPS ablation top-5 bound)
// NOTE: tail-wrap garbage stages are LOAD-BEARING for the vmcnt(4) ledger — do not remove.
#define GBAR  do { asm volatile("" ::: "memory"); __builtin_amdgcn_s_barrier(); asm volatile("" ::: "memory"); } while(0)

#define PHASE(BUF, MH, NH, LA, LB, SBUF, SISB, SUNIT, ST, DOVM)                                   \
  { if (LA){ _Pragma("unroll") for (int ko_=0;ko_<2;ko_++)                                        \
               _Pragma("unroll") for (int ii_=0;ii_<4;ii_++) Afr[ko_][ii_]=rdA(BUF,MH,ii_,ko_); } \
    if (LB){ _Pragma("unroll") for (int ko_=0;ko_<2;ko_++)                                        \
               _Pragma("unroll") for (int jj_=0;jj_<2;jj_++) Bfr[ko_][jj_]=rdB(BUF,NH,jj_,ko_); } \
    stage(SBUF,SISB,SUNIT,ST);                                                                    \
    if (DOVM) asm volatile("s_waitcnt vmcnt(4)" ::: "memory");                                    \
    GBAR;                                                                                         \
    __builtin_amdgcn_s_setprio(1);                                                                \
    _Pragma("unroll") for (int ii_=0;ii_<4;ii_++)                                                 \
      _Pragma("unroll") for (int jj_=0;jj_<2;jj_++)                                               \
        _Pragma("unroll") for (int ko_=0;ko_<2;ko_++)                                             \
          acc[(MH)*4+ii_][(NH)*2+jj_] = __builtin_amdgcn_mfma_f32_16x16x32_bf16(                  \
              Afr[ko_][ii_], Bfr[ko_][jj_], acc[(MH)*4+ii_][(NH)*2+jj_], 0, 0, 0);                \
    __builtin_amdgcn_s_setprio(0);                                                                \
    GBAR; }

__global__ __launch_bounds__(512, 2) void k_gemm256(
    const __hip_bfloat16* __restrict__ A,
    const __hip_bfloat16* __restrict__ Wtl, const __hip_bfloat16* __restrict__ Wtr,
    __hip_bfloat16* __restrict__ Cl, __hip_bfloat16* __restrict__ Cr, int K){
  const __hip_bfloat16* Wt = blockIdx.z ? Wtr : Wtl;
  __hip_bfloat16*       C  = blockIdx.z ? Cr  : Cl;
  __shared__ __align__(128) char lds[131072];   // A: [0,64K)  B: [64K,128K)
  const int tid = threadIdx.x;
  const int w = tid >> 6, lane = tid & 63;
  const int wm = w >> 2, wn = w & 3;
  const int l16 = lane & 15, c4 = lane >> 4;
  const int row0 = blockIdx.x * 256, col0 = blockIdx.y * 256;
  const int NT = K >> 6;

  f32x4 acc[8][4];
  bf16x8 Afr[2][4];   // [ko][ii]  current mh
  bf16x8 Bfr[2][2];   // [ko][jj]  current nh

  const __hip_bfloat16* Ag = A  + (size_t)row0 * K;
  const __hip_bfloat16* Bg = Wt + (size_t)col0 * K;

  auto stage = [&](int buf, int isB, int unit, int t){
    int k0 = (t < NT ? t : t - NT) << 6;        // tail wrap -> dead-region garbage stage
    #pragma unroll
    for (int j = 0; j < 2; j++){
      int u0 = (w*2 + j) * 8;                   // wave-uniform
      int uidx = u0 + (lane >> 3);              // 0..127 within unit
      int row, rs;
      if (!isB){ row = (uidx & 63) | ((uidx & 64) << 1) | (unit << 6);
                 rs  = (u0   & 63) | ((u0   & 64) << 1) | (unit << 6); }
      else     { row = ((uidx & 96) << 1) | (uidx & 31) | (unit << 5);
                 rs  = ((u0   & 96) << 1) | (u0   & 31) | (unit << 5); }
      int chunk = (lane & 7) ^ (uidx & 7);      // inverse-swizzled global source
      const __hip_bfloat16* gp = (isB ? Bg : Ag) + (size_t)row * K + k0 + chunk * 8;
      async16(gp, lds + (isB ? 65536 : 0) + buf * 32768 + rs * 128);
    }
  };

  auto rdA = [&](int buf, int mh, int ii, int ko)->bf16x8{
    int row = wm*128 + mh*64 + ii*16 + l16;
    int chunk = ((ko<<2) + c4) ^ (l16 & 7);
    return *(const bf16x8*)(lds + buf*32768 + row*128 + chunk*16);
  };
  auto rdB = [&](int buf, int nh, int jj, int ko)->bf16x8{
    int row = wn*64 + nh*32 + jj*16 + l16;
    int chunk = ((ko<<2) + c4) ^ (l16 & 7);
    return *(const bf16x8*)(lds + 65536 + buf*32768 + row*128 + chunk*16);
  };

  #pragma unroll
  for (int i = 0; i < 8; i++)
    #pragma unroll
    for (int j = 0; j < 4; j++) acc[i][j] = (f32x4){0.f,0.f,0.f,0.f};

  // prologue: full tile0 + A(1)u0 + B(1)u1, allow last 2 units in flight
  stage(0,0,0,0); stage(0,1,1,0); stage(0,0,1,0); stage(0,1,0,0);
  stage(1,0,0,1); stage(1,1,1,1);
  asm volatile("s_waitcnt vmcnt(4)" ::: "memory");
  GBAR;

  for (int t = 0; t < NT; t += 2){
    PHASE(0, 0, 0, 1, 1, 1, 0, 1, t+1, 0)   // ph1: stage A(t+1)u1 -> buf1
    PHASE(0, 0, 1, 0, 1, 1, 1, 0, t+1, 0)   // ph2: stage B(t+1)u0 -> buf1
    PHASE(0, 1, 1, 1, 0, 0, 0, 0, t+2, 0)   // ph3: stage A(t+2)u0 -> buf0
    PHASE(0, 1, 0, 0, 1, 0, 1, 1, t+2, 1)   // ph4: stage B(t+2)u1 -> buf0, vmcnt(4)
    PHASE(1, 0, 0, 1, 1, 0, 0, 1, t+2, 0)   // ph5: stage A(t+2)u1 -> buf0
    PHASE(1, 0, 1, 0, 1, 0, 1, 0, t+2, 0)   // ph6: stage B(t+2)u0 -> buf0
    PHASE(1, 1, 1, 1, 0, 1, 0, 0, t+3, 0)   // ph7: stage A(t+3)u0 -> buf1
    PHASE(1, 1, 0, 0, 1, 1, 1, 1, t+3, 1)   // ph8: stage B(t+3)u1 -> buf1, vmcnt(4)
  }

  // drain wrapped garbage stages before reusing LDS as C-staging tile
  asm volatile("s_waitcnt vmcnt(0)" ::: "memory");
  GBAR;
  {
    __hip_bfloat16* ct = (__hip_bfloat16*)lds;   // [256][256] bf16 = 128 KiB
    #pragma unroll
    for (int i = 0; i < 8; i++)
      #pragma unroll
      for (int j = 0; j < 4; j++)
        #pragma unroll
        for (int r = 0; r < 4; r++){
          int rl = wm*128 + i*16 + c4*4 + r;
          int cl = wn*64  + j*16 + l16;
          ct[rl*256 + cl] = __float2bfloat16(acc[i][j][r]);
        }
  }
  // ds_write -> barrier -> ds_read requires the writer's lgkmcnt(0) (ISA §8)
  asm volatile("s_waitcnt lgkmcnt(0)" ::: "memory");
  GBAR;
  #pragma unroll
  for (int s = 0; s < 16; s++){
    int seg = s*512 + tid;            // 8192 x 16B
    int rl = seg >> 5, ch = seg & 31;
    uint4 v = *(const uint4*)(lds + rl*512 + ch*16);
    *(uint4*)((char*)(C + (size_t)(row0 + rl)*CDIM + col0) + ch*16) = v;
  }
}

// ---------- fused GATv2 edge phase: 1 wave/block (r8 best config) + 8-edge groups ----------
// r10 post-mortem: attn is NOT chip-level-VALU bound (aggregate VALU ~4us vs 26us measured);
// it is gather-bandwidth bound, limited by IN-FLIGHT BYTES (Little's law): r8 had
// 16 waves/CU x 8 outstanding 16B gathers = 2KB/CU. This version doubles in-flight:
// 8-edge groups, depth-1 ping-pong -> 16 outstanding gathers/wave (4KB/CU). Occupancy
// unchanged (16 wg/CU limit binds before VGPR at ~115). Edge processing order identical
// to r8 -> bit-identical output.
template<int CONCAT>
__global__ __launch_bounds__(64) void k_fused_attn(
    const __hip_bfloat16* __restrict__ XL, const __hip_bfloat16* __restrict__ XR,
    const float* __restrict__ att,
    const int* __restrict__ off, const int* __restrict__ srcs,
    const float* __restrict__ bias, __hip_bfloat16* __restrict__ OUT){
  int lane = threadIdx.x;
  int d = blockIdx.x;

  uint4 xru = *(const uint4*)((const char*)XR + ((size_t)d*CDIM + lane*8)*2);
  f32x2 xr2[4] = {unpk2(xru.x), unpk2(xru.y), unpk2(xru.z), unpk2(xru.w)};
  const f32x2* atp = (const f32x2*)(att + lane*8);
  f32x2 at2[4] = {atp[0], atp[1], atp[2], atp[3]};
  const f32x2 c02 = {0.2f, 0.2f};

  f32x2 acc2[4];
  #pragma unroll
  for (int k = 0; k < 4; k++) acc2[k] = (f32x2){0.f, 0.f};
  float den = 0.f;

  int beg = off[d], end = off[d+1];   // end > beg guaranteed (self-loops appended)

  uint4 rwA[8], rwB[8];

  auto ldgth = [&](int i, uint4* rw){
    int n = end - i;                       // wave-uniform, >= 1
    int s[8];
    s[0] = srcs[i];
    #pragma unroll
    for (int j = 1; j < 8; j++) s[j] = j < n ? srcs[i+j] : s[0];
    #pragma unroll
    for (int j = 0; j < 8; j++)
      rw[j] = *(const uint4*)((const char*)XL + ((size_t)s[j]*CDIM + lane*8)*2);
  };

  auto compute = [&](const uint4* rw, int n){
    #pragma unroll
    for (int e = 0; e < 8; e++){
      if (e < n){                          // wave-uniform branch
        f32x2 xv2[4] = {unpk2(rw[e].x), unpk2(rw[e].y), unpk2(rw[e].z), unpk2(rw[e].w)};
        f32x2 v2 = (f32x2){0.f, 0.f};
        #pragma unroll
        for (int k = 0; k < 4; k++){
          f32x2 m2 = pk_add(xv2[k], xr2[k]);
          f32x2 t2 = pk_mul(m2, c02);
          f32x2 l2 = (f32x2){fmaxf(m2[0], t2[0]), fmaxf(m2[1], t2[1])};  // leaky
          v2 = pk_fma(l2, at2[k], v2);
        }
        float v = v2[0] + v2[1];
        v += __shfl_xor(v, 1); v += __shfl_xor(v, 2); v += __shfl_xor(v, 4);
        float p = __expf(v);
        den += p;
        f32x2 p2 = (f32x2){p, p};
        #pragma unroll
        for (int k = 0; k < 4; k++) acc2[k] = pk_fma(p2, xv2[k], acc2[k]);
      }
    }
  };

  ldgth(beg, rwA);
  int i = beg;
  while (true){
    int iB = i + 8;
    if (iB >= end){ compute(rwA, end - i); break; }
    ldgth(iB, rwB);                        // issue next group before waiting on rwA
    compute(rwA, 8);
    int iA = iB + 8;
    if (iA >= end){ compute(rwB, end - iB); break; }
    ldgth(iA, rwA);
    compute(rwB, 8);
    i = iA;
  }

  float inv = 1.f / (den + 1e-16f);
  const float4* bp = (const float4*)(bias + (CONCAT ? lane*8 : (lane & 7)*8));

  if (CONCAT){
    float4 b0v = bp[0], b1v = bp[1];
    float bb[8] = {b0v.x, b0v.y, b0v.z, b0v.w, b1v.x, b1v.y, b1v.z, b1v.w};
    PK8 pk;
    #pragma unroll
    for (int k = 0; k < 4; k++){
      pk.h[2*k]   = __float2bfloat16(acc2[k][0]*inv + bb[2*k]);
      pk.h[2*k+1] = __float2bfloat16(acc2[k][1]*inv + bb[2*k+1]);
    }
    *(uint4*)((char*)OUT + ((size_t)d*CDIM + lane*8)*2) = pk.v;
  } else {
    float r[8];
    #pragma unroll
    for (int k = 0; k < 4; k++){ r[2*k] = acc2[k][0]*inv; r[2*k+1] = acc2[k][1]*inv; }
    #pragma unroll
    for (int o = 8; o < 64; o <<= 1)
      #pragma unroll
      for (int j = 0; j < 8; j++) r[j] += __shfl_xor(r[j], o);
    if (lane < 8){
      float4 b0v = bp[0], b1v = bp[1];
      float bb[8] = {b0v.x, b0v.y, b0v.z, b0v.w, b1v.x, b1v.y, b1v.z, b1v.w};
      PK8 pk;
      #pragma unroll
      for (int j = 0; j < 8; j++)
        pk.h[j] = __float2bfloat16(r[j]*0.125f + bb[j]);
      *(uint4*)((char*)OUT + ((size_t)d*FDIM + lane*8)*2) = pk.v;
    }
  }
}

// ---------- GraphNorm + ReLU (layers 1-2) ----------
__global__ void k_graphnorm_relu(const __hip_bfloat16* __restrict__ X, const float* __restrict__ w,
    const float* __restrict__ b, const float* __restrict__ ms,
    __hip_bfloat16* __restrict__ Y, int C){
  int g = blockIdx.x;
  int c = threadIdx.x;
  const __hip_bfloat16* xg = X + (size_t)g * NG * C + c;
  __hip_bfloat16* yg = Y + (size_t)g * NG * C + c;
  float v[NG];
  float s1 = 0.f, s2 = 0.f;
  #pragma unroll
  for (int i = 0; i < NG; i++){
    v[i] = __bfloat162float(xg[(size_t)i*C]);
    s1 += v[i]; s2 += v[i]*v[i];
  }
  float mean = s1 * (1.f/NG);
  float m = ms[c];
  float var = s2 * (1.f/NG) - 2.f*m*mean*mean + m*m*mean*mean;
  float inv = rsqrtf(var + 1e-5f);
  float ww = w[c], bb = b[c];
  #pragma unroll
  for (int i = 0; i < NG; i++){
    float y = fmaf(ww * (v[i] - m*mean), inv, bb);
    yg[(size_t)i*C] = __float2bfloat16(y > 0.f ? y : 0.f);
  }
}

// ---------- layer 3: GraphNorm + ReLU + mean-pool + linear [64->2], fused ----------
__global__ void k_norm_pool(const __hip_bfloat16* __restrict__ X, const float* __restrict__ w,
    const float* __restrict__ b, const float* __restrict__ ms,
    const float* __restrict__ Wlin, const float* __restrict__ blin,
    void* out, const unsigned short* __restrict__ xus){
  int g = blockIdx.x, c = threadIdx.x;  // 64 threads, c = channel
  const __hip_bfloat16* xg = X + (size_t)g * NG * FDIM + c;
  float v[NG];
  float s1 = 0.f, s2 = 0.f;
  #pragma unroll
  for (int i = 0; i < NG; i++){
    v[i] = __bfloat162float(xg[(size_t)i*FDIM]);
    s1 += v[i]; s2 += v[i]*v[i];
  }
  float mean = s1 * (1.f/NG);
  float m = ms[c];
  float var = s2 * (1.f/NG) - 2.f*m*mean*mean + m*m*mean*mean;
  float inv = rsqrtf(var + 1e-5f);
  float ww = w[c], bb = b[c];
  float pooled = 0.f;
  #pragma unroll
  for (int i = 0; i < NG; i++){
    float y = fmaf(ww * (v[i] - m*mean), inv, bb);
    pooled += (y > 0.f ? y : 0.f);
  }
  pooled *= (1.f/NG);
  float v0 = pooled * Wlin[c*2 + 0];
  float v1 = pooled * Wlin[c*2 + 1];
  #pragma unroll
  for (int o = 32; o; o >>= 1){ v0 += __shfl_down(v0, o); v1 += __shfl_down(v1, o); }
  if (c == 0){
    float o0 = v0 + blin[0], o1 = v1 + blin[1];
    if (is_f32(xus)){
      ((float*)out)[g*2 + 0] = o0;
      ((float*)out)[g*2 + 1] = o1;
    } else {
      ((__hip_bfloat16*)out)[g*2 + 0] = __float2bfloat16(o0);
      ((__hip_bfloat16*)out)[g*2 + 1] = __float2bfloat16(o1);
    }
  }
}

extern "C" void kernel_launch(void* const* d_in, const int* in_sizes, int n_in,
                              void* d_out, int out_size, void* d_ws, size_t ws_size,
                              hipStream_t stream){
  const int N = NNODES;
  const int E = in_sizes[1];

  const int* esrc = (const int*)d_in[1];
  const int* edst = (const int*)d_in[2];
  const unsigned short* xus = (const unsigned short*)d_in[0];

  // ---- workspace layout ----
  char* ws = (char*)d_ws;
  size_t cursor_b = 0;
  auto alloc = [&](size_t bytes)->char*{
    char* p = ws + cursor_b;
    cursor_b += (bytes + 255) & ~size_t(255);
    return p;
  };

  static const int convIdx[17] = {6,7,8,9,10, 13,14,15,16,17, 20,21,22,23,24, 25,26};
  CArgs ca;
  int cums[18]; cums[0] = 0;
  for (int i = 0; i < 17; i++){
    ca.p[i] = d_in[convIdx[i]];
    cums[i+1] = cums[i] + in_sizes[convIdx[i]];
  }
  memcpy(ca.cum, cums, sizeof(cums));
  int totalConv = cums[17];

  float* conv = (float*)alloc((size_t)totalConv * 4);
  const float* fw[17];
  for (int i = 0; i < 17; i++) fw[i] = conv + cums[i];
  // fw map: 0:att1 1:b1 2:gnw1 3:gnb1 4:gnm1
  //         5:att2 6:b2 7:gnw2 8:gnb2 9:gnm2
  //         10:att3 11:b3 12:gnw3 13:gnb3 14:gnm3 15:Wlin 16:blin

  __hip_bfloat16* XLbf  = (__hip_bfloat16*)alloc((size_t)N * CDIM * 2);
  __hip_bfloat16* XRbf  = (__hip_bfloat16*)alloc((size_t)N * CDIM * 2);
  __hip_bfloat16* OUTbf = (__hip_bfloat16*)alloc((size_t)N * CDIM * 2);   // attn out, pre-norm
  __hip_bfloat16* OUT3  = (__hip_bfloat16*)alloc((size_t)N * FDIM * 2);
  __hip_bfloat16* HBbf  = (__hip_bfloat16*)alloc((size_t)N * CDIM * 2);
  __hip_bfloat16* xbf   = (__hip_bfloat16*)alloc((size_t)N * GIN * 2);
  __hip_bfloat16* Wt[6];
  Wt[0] = (__hip_bfloat16*)alloc((size_t)CDIM * GIN * 2);
  Wt[1] = (__hip_bfloat16*)alloc((size_t)CDIM * GIN * 2);
  Wt[2] = (__hip_bfloat16*)alloc((size_t)CDIM * CDIM * 2);
  Wt[3] = (__hip_bfloat16*)alloc((size_t)CDIM * CDIM * 2);
  Wt[4] = (__hip_bfloat16*)alloc((size_t)CDIM * CDIM * 2);
  Wt[5] = (__hip_bfloat16*)alloc((size_t)CDIM * CDIM * 2);
  int* deg  = (int*)alloc((size_t)N * 4);
  int* off  = (int*)alloc((size_t)(N + 1) * 4);
  int* cur  = (int*)alloc((size_t)N * 4);
  int* srcs = (int*)alloc((size_t)E * 4);

  // ---- convert small vecs (+ zero deg), x->bf16 (+ count degrees), transpose weights ----
  k_convert<<<32, 256, 0, stream>>>(ca, xus, conv, totalConv, deg);
  k_xconv_count<<<2048, 256, 0, stream>>>(d_in[0], xbf, N * GIN, edst, E, deg);
  {
    TArgs ta;
    const void* Ws[6] = {d_in[4], d_in[5], d_in[11], d_in[12], d_in[18], d_in[19]};
    const int   Ks[6] = {GIN, GIN, CDIM, CDIM, CDIM, CDIM};
    for (int i = 0; i < 6; i++){ ta.W[i] = Ws[i]; ta.Wt[i] = Wt[i]; ta.K[i] = Ks[i]; }
    k_transpose_all<<<dim3(CDIM/32, CDIM/32, 6), dim3(32, 8), 0, stream>>>(ta, xus);
  }

  // ---- CSR by dst (payload = src) ----
  k_scan<<<1, 256, 0, stream>>>(deg, off, cur);
  k_fill<<<(E + 255)/256, 256, 0, stream>>>(esrc, edst, E, cur, srcs);

  // ---- 3 GATv2 + GraphNorm + ReLU layers ----
  const float* att_[3] = {fw[0],  fw[5],  fw[10]};
  const float* b_[3]   = {fw[1],  fw[6],  fw[11]};
  const float* gw_[3]  = {fw[2],  fw[7],  fw[12]};
  const float* gb_[3]  = {fw[3],  fw[8],  fw[13]};
  const float* gm_[3]  = {fw[4],  fw[9],  fw[14]};

  // layer 1
  k_gemm256<<<dim3(N/256, CDIM/256, 2), 512, 0, stream>>>(xbf, Wt[0], Wt[1], XLbf, XRbf, GIN);
  k_fused_attn<1><<<N, 64, 0, stream>>>(XLbf, XRbf, att_[0], off, srcs, b_[0], OUTbf);
  k_graphnorm_relu<<<NGRAPH, CDIM, 0, stream>>>(OUTbf, gw_[0], gb_[0], gm_[0], HBbf, CDIM);

  // layer 2
  k_gemm256<<<dim3(N/256, CDIM/256, 2), 512, 0, stream>>>(HBbf, Wt[2], Wt[3], XLbf, XRbf, CDIM);
  k_fused_attn<1><<<N, 64, 0, stream>>>(XLbf, XRbf, att_[1], off, srcs, b_[1], OUTbf);
  k_graphnorm_relu<<<NGRAPH, CDIM, 0, stream>>>(OUTbf, gw_[1], gb_[1], gm_[1], HBbf, CDIM);

  // layer 3
  k_gemm256<<<dim3(N/256, CDIM/256, 2), 512, 0, stream>>>(HBbf, Wt[4], Wt[5], XLbf, XRbf, CDIM);
  k_fused_attn<0><<<N, 64, 0, stream>>>(XLbf, XRbf, att_[2], off, srcs, b_[2], OUT3);
  k_norm_pool<<<NGRAPH, 64, 0, stream>>>(OUT3, gw_[2], gb_[2], gm_[2], fw[15], fw[16], d_out, xus);
}

// Round 12
// 310.530 us; speedup vs baseline: 1.0501x; 1.0313x over previous
//
#include <hip/hip_runtime.h>
#include <hip/hip_bf16.h>
#include <stdint.h>
#include <string.h>

#define NNODES 16384
#define GIN 256      // input feature dim
#define NG 64        // nodes per graph (N/G)
#define NGRAPH 256
#define FDIM 64      // per-head out dim
#define CDIM 512     // H*F

typedef __attribute__((ext_vector_type(8))) short bf16x8;
typedef __attribute__((ext_vector_type(4))) float f32x4;
typedef __attribute__((ext_vector_type(2))) float f32x2;

__device__ __forceinline__ float bf2f(unsigned short u){
  union { unsigned int i; float f; } w; w.i = ((unsigned int)u) << 16; return w.f;
}

// unpack two bf16 packed in a uint to an f32 pair
__device__ __forceinline__ f32x2 unpk2(unsigned int u){
  union { unsigned int i; float f; } a, b;
  a.i = u << 16; b.i = u & 0xffff0000u;
  return (f32x2){a.f, b.f};
}

// CDNA full-rate packed f32 VALU (VOP3P) — one instruction covers 2 channels
__device__ __forceinline__ f32x2 pk_add(f32x2 a, f32x2 b){
  f32x2 d; asm("v_pk_add_f32 %0, %1, %2" : "=v"(d) : "v"(a), "v"(b)); return d;
}
__device__ __forceinline__ f32x2 pk_mul(f32x2 a, f32x2 b){
  f32x2 d; asm("v_pk_mul_f32 %0, %1, %2" : "=v"(d) : "v"(a), "v"(b)); return d;
}
__device__ __forceinline__ f32x2 pk_fma(f32x2 a, f32x2 b, f32x2 c){
  f32x2 d; asm("v_pk_fma_f32 %0, %1, %2, %3" : "=v"(d) : "v"(a), "v"(b), "v"(c)); return d;
}

union PK8 { __hip_bfloat16 h[8]; uint4 v; };

__device__ __forceinline__ void async16(const void* g, void* l){
  __builtin_amdgcn_global_load_lds(
      (const __attribute__((address_space(1))) unsigned int*)g,
      (__attribute__((address_space(3))) unsigned int*)l, 16, 0, 0);
}

// ---------- local dtype detection ----------
__device__ __forceinline__ int is_f32(const unsigned short* __restrict__ x){
  int bad = 0;
  #pragma unroll
  for (int j = 0; j < 64; j++){
    float f = bf2f(x[j*4]);
    if (!(fabsf(f) < 1e4f)) bad++;
  }
  return bad > 4;
}

// ---------- small-vector conversion to fp32 (17 segments) + deg zeroing ----------
struct CArgs {
  const void* p[17];
  int cum[18];
};

__global__ void k_convert(CArgs a, const unsigned short* __restrict__ x,
                          float* __restrict__ dst, int total, int* __restrict__ deg){
  int isf32 = is_f32(x);
  int totAll = total + NNODES;
  for (int idx = blockIdx.x*blockDim.x + threadIdx.x; idx < totAll; idx += gridDim.x*blockDim.x){
    if (idx >= total){ deg[idx - total] = 0; continue; }
    int seg = 0;
    while (idx >= a.cum[seg+1]) seg++;
    int off = idx - a.cum[seg];
    float v;
    if (isf32) v = ((const float*)a.p[seg])[off];
    else       v = bf2f(((const unsigned short*)a.p[seg])[off]);
    dst[idx] = v;
  }
}

// ---------- x -> bf16 + edge degree count (deg pre-zeroed by k_convert) ----------
__global__ void k_xconv_count(const void* __restrict__ xin,
                              __hip_bfloat16* __restrict__ xbf, int total,
                              const int* __restrict__ edst, int E, int* __restrict__ deg){
  int isf32 = is_f32((const unsigned short*)xin);
  for (int idx = blockIdx.x*blockDim.x + threadIdx.x; idx < total; idx += gridDim.x*blockDim.x){
    float v;
    if (isf32) v = ((const float*)xin)[idx];
    else       v = bf2f(((const unsigned short*)xin)[idx]);
    xbf[idx] = __float2bfloat16(v);
  }
  for (int e = blockIdx.x*blockDim.x + threadIdx.x; e < E; e += gridDim.x*blockDim.x)
    atomicAdd(&deg[edst[e]], 1);
}

// ---------- merged transpose from RAW weights ----------
struct TArgs {
  const void* W[6];
  __hip_bfloat16* Wt[6];
  int K[6];
};

__global__ void k_transpose_all(TArgs t, const unsigned short* __restrict__ x){
  int isf32 = is_f32(x);
  int seg = blockIdx.z;
  int K = t.K[seg];
  int n0 = blockIdx.x*32, k0 = blockIdx.y*32;
  if (k0 >= K) return;
  const void* W = t.W[seg];
  __hip_bfloat16* Wt = t.Wt[seg];
  __shared__ float tl[32][33];
  for (int r = threadIdx.y; r < 32; r += 8){
    size_t idx = (size_t)(k0 + r)*CDIM + n0 + threadIdx.x;
    tl[r][threadIdx.x] = isf32 ? ((const float*)W)[idx] : bf2f(((const unsigned short*)W)[idx]);
  }
  __syncthreads();
  for (int r = threadIdx.y; r < 32; r += 8)
    Wt[(size_t)(n0 + r)*K + k0 + threadIdx.x] = __float2bfloat16(tl[threadIdx.x][r]);
}

// ---------- CSR build (by dst), payload = src node ----------
__global__ void k_scan(const int* __restrict__ deg, int* __restrict__ off, int* __restrict__ cur){
  __shared__ int ss[256];
  int t = threadIdx.x;
  const int4* d4 = (const int4*)(deg + t*64);
  int4 buf[16];
  int s = 0;
  #pragma unroll
  for (int j = 0; j < 16; j++){
    buf[j] = d4[j];
    s += buf[j].x + buf[j].y + buf[j].z + buf[j].w;
  }
  ss[t] = s;
  __syncthreads();
  for (int o = 1; o < 256; o <<= 1){
    int v = 0;
    if (t >= o) v = ss[t - o];
    __syncthreads();
    if (t >= o) ss[t] += v;
    __syncthreads();
  }
  int run = ss[t] - s;  // exclusive prefix
  int4* o4 = (int4*)(off + t*64);
  int4* c4 = (int4*)(cur + t*64);
  #pragma unroll
  for (int j = 0; j < 16; j++){
    int4 v;
    v.x = run; run += buf[j].x;
    v.y = run; run += buf[j].y;
    v.z = run; run += buf[j].z;
    v.w = run; run += buf[j].w;
    o4[j] = v; c4[j] = v;
  }
  if (t == 255) off[NNODES] = run;
}

__global__ void k_fill(const int* __restrict__ esrc, const int* __restrict__ edst, int E,
                       int* __restrict__ cur, int* __restrict__ srcs){
  int e = blockIdx.x*blockDim.x + threadIdx.x;
  if (e < E){
    int pos = atomicAdd(&cur[edst[e]], 1);
    srcs[pos] = esrc[e];
  }
}

// ---------- bf16 MFMA GEMM, 256x256 tile, BK=64, 8-wave 8-phase counted-vmcnt schedule ----------
// (verified; <=15us marginal/launch at K=512 per round-6 REPS ablation top-5 bound)
// NOTE: tail-wrap garbage stages are LOAD-BEARING for the vmcnt(4) ledger — do not remove.
#define GBAR  do { asm volatile("" ::: "memory"); __builtin_amdgcn_s_barrier(); asm volatile("" ::: "memory"); } while(0)

#define PHASE(BUF, MH, NH, LA, LB, SBUF, SISB, SUNIT, ST, DOVM)                                   \
  { if (LA){ _Pragma("unroll") for (int ko_=0;ko_<2;ko_++)                                        \
               _Pragma("unroll") for (int ii_=0;ii_<4;ii_++) Afr[ko_][ii_]=rdA(BUF,MH,ii_,ko_); } \
    if (LB){ _Pragma("unroll") for (int ko_=0;ko_<2;ko_++)                                        \
               _Pragma("unroll") for (int jj_=0;jj_<2;jj_++) Bfr[ko_][jj_]=rdB(BUF,NH,jj_,ko_); } \
    stage(SBUF,SISB,SUNIT,ST);                                                                    \
    if (DOVM) asm volatile("s_waitcnt vmcnt(4)" ::: "memory");                                    \
    GBAR;                                                                                         \
    __builtin_amdgcn_s_setprio(1);                                                                \
    _Pragma("unroll") for (int ii_=0;ii_<4;ii_++)                                                 \
      _Pragma("unroll") for (int jj_=0;jj_<2;jj_++)                                               \
        _Pragma("unroll") for (int ko_=0;ko_<2;ko_++)                                             \
          acc[(MH)*4+ii_][(NH)*2+jj_] = __builtin_amdgcn_mfma_f32_16x16x32_bf16(                  \
              Afr[ko_][ii_], Bfr[ko_][jj_], acc[(MH)*4+ii_][(NH)*2+jj_], 0, 0, 0);                \
    __builtin_amdgcn_s_setprio(0);                                                                \
    GBAR; }

__global__ __launch_bounds__(512, 2) void k_gemm256(
    const __hip_bfloat16* __restrict__ A,
    const __hip_bfloat16* __restrict__ Wtl, const __hip_bfloat16* __restrict__ Wtr,
    __hip_bfloat16* __restrict__ Cl, __hip_bfloat16* __restrict__ Cr, int K){
  const __hip_bfloat16* Wt = blockIdx.z ? Wtr : Wtl;
  __hip_bfloat16*       C  = blockIdx.z ? Cr  : Cl;
  __shared__ __align__(128) char lds[131072];   // A: [0,64K)  B: [64K,128K)
  const int tid = threadIdx.x;
  const int w = tid >> 6, lane = tid & 63;
  const int wm = w >> 2, wn = w & 3;
  const int l16 = lane & 15, c4 = lane >> 4;
  const int row0 = blockIdx.x * 256, col0 = blockIdx.y * 256;
  const int NT = K >> 6;

  f32x4 acc[8][4];
  bf16x8 Afr[2][4];   // [ko][ii]  current mh
  bf16x8 Bfr[2][2];   // [ko][jj]  current nh

  const __hip_bfloat16* Ag = A  + (size_t)row0 * K;
  const __hip_bfloat16* Bg = Wt + (size_t)col0 * K;

  auto stage = [&](int buf, int isB, int unit, int t){
    int k0 = (t < NT ? t : t - NT) << 6;        // tail wrap -> dead-region garbage stage
    #pragma unroll
    for (int j = 0; j < 2; j++){
      int u0 = (w*2 + j) * 8;                   // wave-uniform
      int uidx = u0 + (lane >> 3);              // 0..127 within unit
      int row, rs;
      if (!isB){ row = (uidx & 63) | ((uidx & 64) << 1) | (unit << 6);
                 rs  = (u0   & 63) | ((u0   & 64) << 1) | (unit << 6); }
      else     { row = ((uidx & 96) << 1) | (uidx & 31) | (unit << 5);
                 rs  = ((u0   & 96) << 1) | (u0   & 31) | (unit << 5); }
      int chunk = (lane & 7) ^ (uidx & 7);      // inverse-swizzled global source
      const __hip_bfloat16* gp = (isB ? Bg : Ag) + (size_t)row * K + k0 + chunk * 8;
      async16(gp, lds + (isB ? 65536 : 0) + buf * 32768 + rs * 128);
    }
  };

  auto rdA = [&](int buf, int mh, int ii, int ko)->bf16x8{
    int row = wm*128 + mh*64 + ii*16 + l16;
    int chunk = ((ko<<2) + c4) ^ (l16 & 7);
    return *(const bf16x8*)(lds + buf*32768 + row*128 + chunk*16);
  };
  auto rdB = [&](int buf, int nh, int jj, int ko)->bf16x8{
    int row = wn*64 + nh*32 + jj*16 + l16;
    int chunk = ((ko<<2) + c4) ^ (l16 & 7);
    return *(const bf16x8*)(lds + 65536 + buf*32768 + row*128 + chunk*16);
  };

  #pragma unroll
  for (int i = 0; i < 8; i++)
    #pragma unroll
    for (int j = 0; j < 4; j++) acc[i][j] = (f32x4){0.f,0.f,0.f,0.f};

  // prologue: full tile0 + A(1)u0 + B(1)u1, allow last 2 units in flight
  stage(0,0,0,0); stage(0,1,1,0); stage(0,0,1,0); stage(0,1,0,0);
  stage(1,0,0,1); stage(1,1,1,1);
  asm volatile("s_waitcnt vmcnt(4)" ::: "memory");
  GBAR;

  for (int t = 0; t < NT; t += 2){
    PHASE(0, 0, 0, 1, 1, 1, 0, 1, t+1, 0)   // ph1: stage A(t+1)u1 -> buf1
    PHASE(0, 0, 1, 0, 1, 1, 1, 0, t+1, 0)   // ph2: stage B(t+1)u0 -> buf1
    PHASE(0, 1, 1, 1, 0, 0, 0, 0, t+2, 0)   // ph3: stage A(t+2)u0 -> buf0
    PHASE(0, 1, 0, 0, 1, 0, 1, 1, t+2, 1)   // ph4: stage B(t+2)u1 -> buf0, vmcnt(4)
    PHASE(1, 0, 0, 1, 1, 0, 0, 1, t+2, 0)   // ph5: stage A(t+2)u1 -> buf0
    PHASE(1, 0, 1, 0, 1, 0, 1, 0, t+2, 0)   // ph6: stage B(t+2)u0 -> buf0
    PHASE(1, 1, 1, 1, 0, 1, 0, 0, t+3, 0)   // ph7: stage A(t+3)u0 -> buf1
    PHASE(1, 1, 0, 0, 1, 1, 1, 1, t+3, 1)   // ph8: stage B(t+3)u1 -> buf1, vmcnt(4)
  }

  // drain wrapped garbage stages before reusing LDS as C-staging tile
  asm volatile("s_waitcnt vmcnt(0)" ::: "memory");
  GBAR;
  {
    __hip_bfloat16* ct = (__hip_bfloat16*)lds;   // [256][256] bf16 = 128 KiB
    #pragma unroll
    for (int i = 0; i < 8; i++)
      #pragma unroll
      for (int j = 0; j < 4; j++)
        #pragma unroll
        for (int r = 0; r < 4; r++){
          int rl = wm*128 + i*16 + c4*4 + r;
          int cl = wn*64  + j*16 + l16;
          ct[rl*256 + cl] = __float2bfloat16(acc[i][j][r]);
        }
  }
  // ds_write -> barrier -> ds_read requires the writer's lgkmcnt(0) (ISA §8)
  asm volatile("s_waitcnt lgkmcnt(0)" ::: "memory");
  GBAR;
  #pragma unroll
  for (int s = 0; s < 16; s++){
    int seg = s*512 + tid;            // 8192 x 16B
    int rl = seg >> 5, ch = seg & 31;
    uint4 v = *(const uint4*)(lds + rl*512 + ch*16);
    *(uint4*)((char*)(C + (size_t)(row0 + rl)*CDIM + col0) + ch*16) = v;
  }
}

// ---------- fused GATv2 edge phase: 1 wave/block, packed-f32 VALU (r8 best: 312.5us) ----------
// Session-converged config. Attn is at the random-row gather cache-BW floor
// (~147MB/launch at ~5.6 TB/s effective L2/L3 ≈ 26us): ILP widening (r11, 2x in-flight)
// and occupancy/node-mapping variants (r9, r10) were all null or negative.
template<int CONCAT>
__global__ __launch_bounds__(64) void k_fused_attn(
    const __hip_bfloat16* __restrict__ XL, const __hip_bfloat16* __restrict__ XR,
    const float* __restrict__ att,
    const int* __restrict__ off, const int* __restrict__ srcs,
    const float* __restrict__ bias, __hip_bfloat16* __restrict__ OUT){
  int lane = threadIdx.x;
  int d = blockIdx.x;

  uint4 xru = *(const uint4*)((const char*)XR + ((size_t)d*CDIM + lane*8)*2);
  f32x2 xr2[4] = {unpk2(xru.x), unpk2(xru.y), unpk2(xru.z), unpk2(xru.w)};
  const f32x2* atp = (const f32x2*)(att + lane*8);
  f32x2 at2[4] = {atp[0], atp[1], atp[2], atp[3]};
  const f32x2 c02 = {0.2f, 0.2f};

  f32x2 acc2[4];
  #pragma unroll
  for (int k = 0; k < 4; k++) acc2[k] = (f32x2){0.f, 0.f};
  float den = 0.f;

  int beg = off[d], end = off[d+1];   // end > beg guaranteed (self-loops appended)

  uint4 rwA[4], rwB[4];

  auto ldgth = [&](int i, uint4* rw){
    int n = end - i;                       // wave-uniform, >= 1
    int s0 = srcs[i];
    int s1 = n > 1 ? srcs[i+1] : s0;
    int s2 = n > 2 ? srcs[i+2] : s0;
    int s3 = n > 3 ? srcs[i+3] : s0;
    rw[0] = *(const uint4*)((const char*)XL + ((size_t)s0*CDIM + lane*8)*2);
    rw[1] = *(const uint4*)((const char*)XL + ((size_t)s1*CDIM + lane*8)*2);
    rw[2] = *(const uint4*)((const char*)XL + ((size_t)s2*CDIM + lane*8)*2);
    rw[3] = *(const uint4*)((const char*)XL + ((size_t)s3*CDIM + lane*8)*2);
  };

  auto compute = [&](const uint4* rw, int n){
    #pragma unroll
    for (int e = 0; e < 4; e++){
      if (e < n){                          // wave-uniform branch
        f32x2 xv2[4] = {unpk2(rw[e].x), unpk2(rw[e].y), unpk2(rw[e].z), unpk2(rw[e].w)};
        f32x2 v2 = (f32x2){0.f, 0.f};
        #pragma unroll
        for (int k = 0; k < 4; k++){
          f32x2 m2 = pk_add(xv2[k], xr2[k]);
          f32x2 t2 = pk_mul(m2, c02);
          f32x2 l2 = (f32x2){fmaxf(m2[0], t2[0]), fmaxf(m2[1], t2[1])};  // leaky
          v2 = pk_fma(l2, at2[k], v2);
        }
        float v = v2[0] + v2[1];
        v += __shfl_xor(v, 1); v += __shfl_xor(v, 2); v += __shfl_xor(v, 4);
        float p = __expf(v);
        den += p;
        f32x2 p2 = (f32x2){p, p};
        #pragma unroll
        for (int k = 0; k < 4; k++) acc2[k] = pk_fma(p2, xv2[k], acc2[k]);
      }
    }
  };

  ldgth(beg, rwA);
  int i = beg;
  while (true){
    int iB = i + 4;
    if (iB >= end){ compute(rwA, end - i); break; }
    ldgth(iB, rwB);                        // issue next group before waiting on rwA
    compute(rwA, 4);
    int iA = iB + 4;
    if (iA >= end){ compute(rwB, end - iB); break; }
    ldgth(iA, rwA);
    compute(rwB, 4);
    i = iA;
  }

  float inv = 1.f / (den + 1e-16f);
  const float4* bp = (const float4*)(bias + (CONCAT ? lane*8 : (lane & 7)*8));

  if (CONCAT){
    float4 b0v = bp[0], b1v = bp[1];
    float bb[8] = {b0v.x, b0v.y, b0v.z, b0v.w, b1v.x, b1v.y, b1v.z, b1v.w};
    PK8 pk;
    #pragma unroll
    for (int k = 0; k < 4; k++){
      pk.h[2*k]   = __float2bfloat16(acc2[k][0]*inv + bb[2*k]);
      pk.h[2*k+1] = __float2bfloat16(acc2[k][1]*inv + bb[2*k+1]);
    }
    *(uint4*)((char*)OUT + ((size_t)d*CDIM + lane*8)*2) = pk.v;
  } else {
    float r[8];
    #pragma unroll
    for (int k = 0; k < 4; k++){ r[2*k] = acc2[k][0]*inv; r[2*k+1] = acc2[k][1]*inv; }
    #pragma unroll
    for (int o = 8; o < 64; o <<= 1)
      #pragma unroll
      for (int j = 0; j < 8; j++) r[j] += __shfl_xor(r[j], o);
    if (lane < 8){
      float4 b0v = bp[0], b1v = bp[1];
      float bb[8] = {b0v.x, b0v.y, b0v.z, b0v.w, b1v.x, b1v.y, b1v.z, b1v.w};
      PK8 pk;
      #pragma unroll
      for (int j = 0; j < 8; j++)
        pk.h[j] = __float2bfloat16(r[j]*0.125f + bb[j]);
      *(uint4*)((char*)OUT + ((size_t)d*FDIM + lane*8)*2) = pk.v;
    }
  }
}

// ---------- GraphNorm + ReLU (layers 1-2) ----------
__global__ void k_graphnorm_relu(const __hip_bfloat16* __restrict__ X, const float* __restrict__ w,
    const float* __restrict__ b, const float* __restrict__ ms,
    __hip_bfloat16* __restrict__ Y, int C){
  int g = blockIdx.x;
  int c = threadIdx.x;
  const __hip_bfloat16* xg = X + (size_t)g * NG * C + c;
  __hip_bfloat16* yg = Y + (size_t)g * NG * C + c;
  float v[NG];
  float s1 = 0.f, s2 = 0.f;
  #pragma unroll
  for (int i = 0; i < NG; i++){
    v[i] = __bfloat162float(xg[(size_t)i*C]);
    s1 += v[i]; s2 += v[i]*v[i];
  }
  float mean = s1 * (1.f/NG);
  float m = ms[c];
  float var = s2 * (1.f/NG) - 2.f*m*mean*mean + m*m*mean*mean;
  float inv = rsqrtf(var + 1e-5f);
  float ww = w[c], bb = b[c];
  #pragma unroll
  for (int i = 0; i < NG; i++){
    float y = fmaf(ww * (v[i] - m*mean), inv, bb);
    yg[(size_t)i*C] = __float2bfloat16(y > 0.f ? y : 0.f);
  }
}

// ---------- layer 3: GraphNorm + ReLU + mean-pool + linear [64->2], fused ----------
__global__ void k_norm_pool(const __hip_bfloat16* __restrict__ X, const float* __restrict__ w,
    const float* __restrict__ b, const float* __restrict__ ms,
    const float* __restrict__ Wlin, const float* __restrict__ blin,
    void* out, const unsigned short* __restrict__ xus){
  int g = blockIdx.x, c = threadIdx.x;  // 64 threads, c = channel
  const __hip_bfloat16* xg = X + (size_t)g * NG * FDIM + c;
  float v[NG];
  float s1 = 0.f, s2 = 0.f;
  #pragma unroll
  for (int i = 0; i < NG; i++){
    v[i] = __bfloat162float(xg[(size_t)i*FDIM]);
    s1 += v[i]; s2 += v[i]*v[i];
  }
  float mean = s1 * (1.f/NG);
  float m = ms[c];
  float var = s2 * (1.f/NG) - 2.f*m*mean*mean + m*m*mean*mean;
  float inv = rsqrtf(var + 1e-5f);
  float ww = w[c], bb = b[c];
  float pooled = 0.f;
  #pragma unroll
  for (int i = 0; i < NG; i++){
    float y = fmaf(ww * (v[i] - m*mean), inv, bb);
    pooled += (y > 0.f ? y : 0.f);
  }
  pooled *= (1.f/NG);
  float v0 = pooled * Wlin[c*2 + 0];
  float v1 = pooled * Wlin[c*2 + 1];
  #pragma unroll
  for (int o = 32; o; o >>= 1){ v0 += __shfl_down(v0, o); v1 += __shfl_down(v1, o); }
  if (c == 0){
    float o0 = v0 + blin[0], o1 = v1 + blin[1];
    if (is_f32(xus)){
      ((float*)out)[g*2 + 0] = o0;
      ((float*)out)[g*2 + 1] = o1;
    } else {
      ((__hip_bfloat16*)out)[g*2 + 0] = __float2bfloat16(o0);
      ((__hip_bfloat16*)out)[g*2 + 1] = __float2bfloat16(o1);
    }
  }
}

extern "C" void kernel_launch(void* const* d_in, const int* in_sizes, int n_in,
                              void* d_out, int out_size, void* d_ws, size_t ws_size,
                              hipStream_t stream){
  const int N = NNODES;
  const int E = in_sizes[1];

  const int* esrc = (const int*)d_in[1];
  const int* edst = (const int*)d_in[2];
  const unsigned short* xus = (const unsigned short*)d_in[0];

  // ---- workspace layout ----
  char* ws = (char*)d_ws;
  size_t cursor_b = 0;
  auto alloc = [&](size_t bytes)->char*{
    char* p = ws + cursor_b;
    cursor_b += (bytes + 255) & ~size_t(255);
    return p;
  };

  static const int convIdx[17] = {6,7,8,9,10, 13,14,15,16,17, 20,21,22,23,24, 25,26};
  CArgs ca;
  int cums[18]; cums[0] = 0;
  for (int i = 0; i < 17; i++){
    ca.p[i] = d_in[convIdx[i]];
    cums[i+1] = cums[i] + in_sizes[convIdx[i]];
  }
  memcpy(ca.cum, cums, sizeof(cums));
  int totalConv = cums[17];

  float* conv = (float*)alloc((size_t)totalConv * 4);
  const float* fw[17];
  for (int i = 0; i < 17; i++) fw[i] = conv + cums[i];
  // fw map: 0:att1 1:b1 2:gnw1 3:gnb1 4:gnm1
  //         5:att2 6:b2 7:gnw2 8:gnb2 9:gnm2
  //         10:att3 11:b3 12:gnw3 13:gnb3 14:gnm3 15:Wlin 16:blin

  __hip_bfloat16* XLbf  = (__hip_bfloat16*)alloc((size_t)N * CDIM * 2);
  __hip_bfloat16* XRbf  = (__hip_bfloat16*)alloc((size_t)N * CDIM * 2);
  __hip_bfloat16* OUTbf = (__hip_bfloat16*)alloc((size_t)N * CDIM * 2);   // attn out, pre-norm
  __hip_bfloat16* OUT3  = (__hip_bfloat16*)alloc((size_t)N * FDIM * 2);
  __hip_bfloat16* HBbf  = (__hip_bfloat16*)alloc((size_t)N * CDIM * 2);
  __hip_bfloat16* xbf   = (__hip_bfloat16*)alloc((size_t)N * GIN * 2);
  __hip_bfloat16* Wt[6];
  Wt[0] = (__hip_bfloat16*)alloc((size_t)CDIM * GIN * 2);
  Wt[1] = (__hip_bfloat16*)alloc((size_t)CDIM * GIN * 2);
  Wt[2] = (__hip_bfloat16*)alloc((size_t)CDIM * CDIM * 2);
  Wt[3] = (__hip_bfloat16*)alloc((size_t)CDIM * CDIM * 2);
  Wt[4] = (__hip_bfloat16*)alloc((size_t)CDIM * CDIM * 2);
  Wt[5] = (__hip_bfloat16*)alloc((size_t)CDIM * CDIM * 2);
  int* deg  = (int*)alloc((size_t)N * 4);
  int* off  = (int*)alloc((size_t)(N + 1) * 4);
  int* cur  = (int*)alloc((size_t)N * 4);
  int* srcs = (int*)alloc((size_t)E * 4);

  // ---- convert small vecs (+ zero deg), x->bf16 (+ count degrees), transpose weights ----
  k_convert<<<32, 256, 0, stream>>>(ca, xus, conv, totalConv, deg);
  k_xconv_count<<<2048, 256, 0, stream>>>(d_in[0], xbf, N * GIN, edst, E, deg);
  {
    TArgs ta;
    const void* Ws[6] = {d_in[4], d_in[5], d_in[11], d_in[12], d_in[18], d_in[19]};
    const int   Ks[6] = {GIN, GIN, CDIM, CDIM, CDIM, CDIM};
    for (int i = 0; i < 6; i++){ ta.W[i] = Ws[i]; ta.Wt[i] = Wt[i]; ta.K[i] = Ks[i]; }
    k_transpose_all<<<dim3(CDIM/32, CDIM/32, 6), dim3(32, 8), 0, stream>>>(ta, xus);
  }

  // ---- CSR by dst (payload = src) ----
  k_scan<<<1, 256, 0, stream>>>(deg, off, cur);
  k_fill<<<(E + 255)/256, 256, 0, stream>>>(esrc, edst, E, cur, srcs);

  // ---- 3 GATv2 + GraphNorm + ReLU layers ----
  const float* att_[3] = {fw[0],  fw[5],  fw[10]};
  const float* b_[3]   = {fw[1],  fw[6],  fw[11]};
  const float* gw_[3]  = {fw[2],  fw[7],  fw[12]};
  const float* gb_[3]  = {fw[3],  fw[8],  fw[13]};
  const float* gm_[3]  = {fw[4],  fw[9],  fw[14]};

  // layer 1
  k_gemm256<<<dim3(N/256, CDIM/256, 2), 512, 0, stream>>>(xbf, Wt[0], Wt[1], XLbf, XRbf, GIN);
  k_fused_attn<1><<<N, 64, 0, stream>>>(XLbf, XRbf, att_[0], off, srcs, b_[0], OUTbf);
  k_graphnorm_relu<<<NGRAPH, CDIM, 0, stream>>>(OUTbf, gw_[0], gb_[0], gm_[0], HBbf, CDIM);

  // layer 2
  k_gemm256<<<dim3(N/256, CDIM/256, 2), 512, 0, stream>>>(HBbf, Wt[2], Wt[3], XLbf, XRbf, CDIM);
  k_fused_attn<1><<<N, 64, 0, stream>>>(XLbf, XRbf, att_[1], off, srcs, b_[1], OUTbf);
  k_graphnorm_relu<<<NGRAPH, CDIM, 0, stream>>>(OUTbf, gw_[1], gb_[1], gm_[1], HBbf, CDIM);

  // layer 3
  k_gemm256<<<dim3(N/256, CDIM/256, 2), 512, 0, stream>>>(HBbf, Wt[4], Wt[5], XLbf, XRbf, CDIM);
  k_fused_attn<0><<<N, 64, 0, stream>>>(XLbf, XRbf, att_[2], off, srcs, b_[2], OUT3);
  k_norm_pool<<<NGRAPH, 64, 0, stream>>>(OUT3, gw_[2], gb_[2], gm_[2], fw[15], fw[16], d_out, xus);
}